// Round 5
// baseline (215.550 us; speedup 1.0000x reference)
//
#include <hip/hip_runtime.h>
#include <hip/hip_bf16.h>
#include <stdint.h>

typedef unsigned short u16;
typedef uint32_t u32;
typedef unsigned long long u64;
typedef __attribute__((ext_vector_type(8))) short bf16x8;
typedef __attribute__((ext_vector_type(4))) float f32x4;
typedef __attribute__((ext_vector_type(16))) float f32x16;
typedef __attribute__((ext_vector_type(4))) u32 u32x4;

#define T_SEQ 2048

__device__ __forceinline__ float bf2f(u16 u) {
  union { u32 i; float f; } v; v.i = ((u32)u) << 16; return v.f;
}
__device__ __forceinline__ u16 f2bf(float f) {
  union { float f; u32 i; } v; v.f = f;
  u32 u = v.i;
  return (u16)((u + 0x7fffu + ((u >> 16) & 1u)) >> 16);
}

#if __has_builtin(__builtin_amdgcn_exp2f)
#define EXP2F(x) __builtin_amdgcn_exp2f(x)
#else
#define EXP2F(x) exp2f(x)
#endif

// truncating bf16 pair pack: {hi[31:16], lo[31:16]}
__device__ __forceinline__ u32 permpack(float lo, float hi) {
#if __has_builtin(__builtin_amdgcn_perm)
  return __builtin_amdgcn_perm(__float_as_uint(hi), __float_as_uint(lo), 0x07060302u);
#else
  return (__float_as_uint(hi) & 0xFFFF0000u) | (__float_as_uint(lo) >> 16);
#endif
}

__device__ __forceinline__ void gload_lds16(const void* g, void* l) {
  __builtin_amdgcn_global_load_lds(
      (const __attribute__((address_space(1))) void*)g,
      (__attribute__((address_space(3))) void*)l, 16, 0, 0);
}

// ---------------- fp32 -> bf16 converts ----------------
__global__ __launch_bounds__(256) void cvt_kernel(const float* __restrict__ src,
                                                  u16* __restrict__ dst, int n) {
  int i = (blockIdx.x * 256 + threadIdx.x) * 4;
  if (i + 3 < n) {
    const float4 v = *(const float4*)(src + i);
    ushort4 o;
    o.x = f2bf(v.x); o.y = f2bf(v.y); o.z = f2bf(v.z); o.w = f2bf(v.w);
    *(ushort4*)(dst + i) = o;
  }
}

__global__ __launch_bounds__(256) void cvt4_kernel(
    const float* __restrict__ s0, const float* __restrict__ s1,
    const float* __restrict__ s2, const float* __restrict__ s3,
    u16* __restrict__ dst) {
  const int z = blockIdx.y;
  const float* src = (z == 0) ? s0 : (z == 1) ? s1 : (z == 2) ? s2 : s3;
  int i = (blockIdx.x * 256 + threadIdx.x) * 4;
  const float4 v = *(const float4*)(src + i);
  ushort4 o;
  o.x = f2bf(v.x); o.y = f2bf(v.y); o.z = f2bf(v.z); o.w = f2bf(v.w);
  *(ushort4*)(dst + (size_t)z * 1048576 + i) = o;
}

// ---------------- GEMM core: C[128x64] += A[128xK] * B[64xK]^T, K=1024 ----
__device__ __forceinline__ void gemm_core_128x64(
    f32x4 acc[2][4], const u16* __restrict__ A, const u16* __restrict__ Bw,
    int bm, int bn, u16* As, u16* Bs)
{
  const int tid = threadIdx.x;
  const int w = tid >> 6, lane = tid & 63, g = lane >> 4, c = lane & 15;
  for (int k0 = 0; k0 < 1024; k0 += 64) {
    __syncthreads();
    #pragma unroll
    for (int is = 0; is < 4; ++is) {
      int o = (is*4 + w)*1024 + lane*16;
      int row = o >> 7, c16 = (o >> 4) & 7;
      gload_lds16(A + (size_t)(bm*128 + row)*1024 + k0 + (c16 ^ (row & 7))*8,
                  (char*)As + (is*4 + w)*1024);
    }
    #pragma unroll
    for (int is = 0; is < 2; ++is) {
      int o = (is*4 + w)*1024 + lane*16;
      int row = o >> 7, c16 = (o >> 4) & 7;
      gload_lds16(Bw + (size_t)(bn*64 + row)*1024 + k0 + (c16 ^ (row & 7))*8,
                  (char*)Bs + (is*4 + w)*1024);
    }
    __syncthreads();
    bf16x8 af[2][2], bfr[4][2];
    #pragma unroll
    for (int mf = 0; mf < 2; ++mf)
      #pragma unroll
      for (int kc = 0; kc < 2; ++kc) {
        int row = w*32 + mf*16 + c;
        int colb = kc*64 + g*16;
        af[mf][kc] = *(const bf16x8*)((const char*)As + row*128 + (colb ^ ((row & 7) << 4)));
      }
    #pragma unroll
    for (int nf = 0; nf < 4; ++nf)
      #pragma unroll
      for (int kc = 0; kc < 2; ++kc) {
        int row = nf*16 + c;
        int colb = kc*64 + g*16;
        bfr[nf][kc] = *(const bf16x8*)((const char*)Bs + row*128 + (colb ^ ((row & 7) << 4)));
      }
    #pragma unroll
    for (int mf = 0; mf < 2; ++mf)
      #pragma unroll
      for (int nf = 0; nf < 4; ++nf)
        #pragma unroll
        for (int kc = 0; kc < 2; ++kc)
          acc[mf][nf] = __builtin_amdgcn_mfma_f32_16x16x32_bf16(
              af[mf][kc], bfr[nf][kc], acc[mf][nf], 0, 0, 0);
  }
}

// ---------------- QKV projection ----------------
// Q is scaled by DH^-0.5 * log2(e) so attention softmax runs in exp2 domain.
__global__ __launch_bounds__(256, 2) void gemm_qkv(
    const u16* __restrict__ Abf, const u16* __restrict__ Wbf,
    const float* __restrict__ bq, const float* __restrict__ bk,
    const float* __restrict__ bv, u16* __restrict__ qkvh)
{
  __shared__ __align__(16) u16 As[128*64];
  __shared__ __align__(16) u16 Bs[64*64];
  f32x4 acc[2][4];
  #pragma unroll
  for (int mf = 0; mf < 2; ++mf)
    #pragma unroll
    for (int nf = 0; nf < 4; ++nf) acc[mf][nf] = (f32x4){0.f,0.f,0.f,0.f};
  const int z = blockIdx.z;
  gemm_core_128x64(acc, Abf, Wbf + (size_t)z*1048576, blockIdx.x, blockIdx.y, As, Bs);
  const float* bias = (z == 0) ? bq : (z == 1) ? bk : bv;
  const float scl = (z == 0) ? 0.18033688011112043f : 1.0f;  // 0.125 * log2(e)
  u16* dst = qkvh + (size_t)z * 4194304;
  const int tid = threadIdx.x, w = tid >> 6, lane = tid & 63, g = lane >> 4, c = lane & 15;
  #pragma unroll
  for (int mf = 0; mf < 2; ++mf)
    #pragma unroll
    for (int nf = 0; nf < 4; ++nf) {
      int col = blockIdx.y*64 + nf*16 + c;
      float bcol = bias[col];
      int h = col >> 6, d = col & 63;
      #pragma unroll
      for (int r = 0; r < 4; ++r) {
        int row = blockIdx.x*128 + w*32 + mf*16 + g*4 + r;
        int t = row >> 1, bb = row & 1;
        float v = (acc[mf][nf][r] + bcol) * scl;
        dst[(size_t)(bb*16 + h)*131072 + (size_t)t*64 + d] = f2bf(v);
      }
    }
}

// ---------------- output projection ----------------
__global__ __launch_bounds__(256, 2) void gemm_out(
    const u16* __restrict__ ctx2, const u16* __restrict__ Wobf,
    const float* __restrict__ bo, float* __restrict__ out)
{
  __shared__ __align__(16) u16 As[128*64];
  __shared__ __align__(16) u16 Bs[64*64];
  f32x4 acc[2][4];
  #pragma unroll
  for (int mf = 0; mf < 2; ++mf)
    #pragma unroll
    for (int nf = 0; nf < 4; ++nf) acc[mf][nf] = (f32x4){0.f,0.f,0.f,0.f};
  gemm_core_128x64(acc, ctx2, Wobf, blockIdx.x, blockIdx.y, As, Bs);
  const int tid = threadIdx.x, w = tid >> 6, lane = tid & 63, g = lane >> 4, c = lane & 15;
  #pragma unroll
  for (int mf = 0; mf < 2; ++mf)
    #pragma unroll
    for (int nf = 0; nf < 4; ++nf) {
      int col = blockIdx.y*64 + nf*16 + c;
      float bcol = bo[col];
      #pragma unroll
      for (int r = 0; r < 4; ++r) {
        int row = blockIdx.x*128 + w*32 + mf*16 + g*4 + r;
        out[(size_t)row*1024 + col] = acc[mf][nf][r] + bcol;
      }
    }
}

// ---------------- V transpose + column sums ----------------
__global__ __launch_bounds__(256) void vtrans_kernel(const u16* __restrict__ Vh,
                                                     u16* __restrict__ Vt,
                                                     float* __restrict__ vs) {
  __shared__ u16 tile[64][72];
  const int bh = blockIdx.x >> 5, tc = blockIdx.x & 31;
  const int t0 = tc * 64;
  const int tid = threadIdx.x;
  {
    const int tl = tid >> 2, d0 = (tid & 3) * 16;
    const u16* src = Vh + (size_t)bh*131072 + (size_t)(t0 + tl)*64 + d0;
    bf16x8 a = *(const bf16x8*)src;
    bf16x8 b2 = *(const bf16x8*)(src + 8);
    #pragma unroll
    for (int j = 0; j < 8; ++j) {
      tile[d0 + j][tl] = (u16)a[j];
      tile[d0 + 8 + j][tl] = (u16)b2[j];
    }
  }
  __syncthreads();
  {
    const int d = tid >> 2, tq = (tid & 3) * 16;
    bf16x8 o0, o1;
    float s = 0.f;
    #pragma unroll
    for (int j = 0; j < 8; ++j) {
      u16 x0 = tile[d][tq + j], x1 = tile[d][tq + 8 + j];
      o0[j] = (short)x0; o1[j] = (short)x1;
      s += bf2f(x0) + bf2f(x1);
    }
    u16* dst = Vt + (size_t)bh*131072 + (size_t)d*2048 + t0 + tq;
    *(bf16x8*)dst = o0;
    *(bf16x8*)(dst + 8) = o1;
    s += __shfl_xor(s, 1, 64);
    s += __shfl_xor(s, 2, 64);
    if ((tid & 3) == 0) atomicAdd(&vs[bh*64 + d], s);
  }
}

// ---------------- flash attention: KV-split flash-decoding ----------------
// grid 3072 = 8 XCD x 4 bh x 96 (qt,chunk) pairs. 1-wave blocks, no LDS/barriers.
// qt<32: single chunk, writes ctx2 directly. qt>=32: 2 chunks, each writes
// unnormalized partial (bf16 cacc, f32 m/l); combine_kernel merges.
// Scores are in exp2 domain (log2e folded into Q scale).
#define ZERO16 (f32x16){0.f,0.f,0.f,0.f,0.f,0.f,0.f,0.f,0.f,0.f,0.f,0.f,0.f,0.f,0.f,0.f}
#define NEGINF (-__builtin_inff())

__global__ __launch_bounds__(64, 4) void flash_attn(
    const u16* __restrict__ Qh, const u16* __restrict__ Kh,
    const u16* __restrict__ Vt, const int* __restrict__ kpm,
    const float* __restrict__ vsum, u16* __restrict__ ctx2,
    u16* __restrict__ pctx, float* __restrict__ pml)
{
  const int lane = threadIdx.x;
  const int l31 = lane & 31, hi = lane >> 5;

  const int id = blockIdx.x;
  const int xcd = id & 7, rest = id >> 3;
  const int bh = xcd * 4 + (rest & 3);
  const int pp = rest >> 2;              // 0..95
  int qt, ch, NS;
  if (pp < 32) { qt = pp; ch = 0; NS = 1; }
  else { int uu = pp - 32; qt = 32 + (uu >> 1); ch = uu & 1; NS = 2; }
  const int b = bh >> 4, h = bh & 15;
  const int q0 = qt * 32;
  const size_t hbase = (size_t)bh * 131072;
  const int nt = (qt >> 1) + 1;
  int lo, hicap;
  if (NS == 1) { lo = 0; hicap = nt; }
  else { int h1 = nt >> 1; lo = ch ? h1 : 0; hicap = ch ? nt : h1; }
  const int q = q0 + l31;

  // Q fragments (B-operand): lane holds Q[q][k = kt*16 + hi*8 + j]
  bf16x8 qfrag[4];
  #pragma unroll
  for (int kt = 0; kt < 4; ++kt)
    qfrag[kt] = *(const bf16x8*)(Qh + hbase + (size_t)q*64 + kt*16 + hi*8);

  // K fragments (A-operand) for first tile
  bf16x8 kreg[2][4];
  #pragma unroll
  for (int sub = 0; sub < 2; ++sub)
    #pragma unroll
    for (int kt = 0; kt < 4; ++kt)
      kreg[sub][kt] = *(const bf16x8*)(Kh + hbase + (size_t)(lo*64 + sub*32 + l31)*64 + kt*16 + hi*8);

  int kpmv_cur = kpm[b*T_SEQ + lo*64 + lane];
  int kpmv_nxt = 0;

  float mrow = NEGINF, lrow = 0.f;
  f32x16 cacc0 = ZERO16, cacc1 = ZERO16;

  for (int t = lo; t < hicap; ++t) {
    const int s0 = t * 64;
    const bool notLast = (t + 1 < hicap);
    const bool diag = (t == nt - 1);

    // V^T fragments (A-operand): Vt[db*32 + l31][s0 + ks*16 + hi*8 + j]
    bf16x8 vf[2][4];
    #pragma unroll
    for (int db = 0; db < 2; ++db)
      #pragma unroll
      for (int ks = 0; ks < 4; ++ks)
        vf[db][ks] = *(const bf16x8*)(Vt + hbase + (size_t)(db*32 + l31)*2048 + s0 + ks*16 + hi*8);

    // S^T = K Q^T : lane owns q=l31; reg i: kv = s0 + sub*32 + 4*hi + (i&3) + 8*(i>>2)
    f32x16 st0 = ZERO16, st1 = ZERO16;
    __builtin_amdgcn_s_setprio(1);
    #pragma unroll
    for (int kt = 0; kt < 4; ++kt) {
      st0 = __builtin_amdgcn_mfma_f32_32x32x16_bf16(kreg[0][kt], qfrag[kt], st0, 0, 0, 0);
      st1 = __builtin_amdgcn_mfma_f32_32x32x16_bf16(kreg[1][kt], qfrag[kt], st1, 0, 0, 0);
    }
    __builtin_amdgcn_s_setprio(0);

    // prefetch K(t+1) + kpm(t+1)
    if (notLast) {
      #pragma unroll
      for (int sub = 0; sub < 2; ++sub)
        #pragma unroll
        for (int kt = 0; kt < 4; ++kt)
          kreg[sub][kt] = *(const bf16x8*)(Kh + hbase + (size_t)(s0 + 64 + sub*32 + l31)*64 + kt*16 + hi*8);
      kpmv_nxt = kpm[b*T_SEQ + s0 + 64 + lane];
    }

    // mask + online softmax (per-lane, exp2 domain)
    {
      const u64 mask = __ballot(kpmv_cur != 0);
      const u32 m0 = (u32)mask, m1 = (u32)(mask >> 32);
      const u64 m4 = mask >> 4;
      const u32 m4l = (u32)m4, m4h = (u32)(m4 >> 32);
      const u32 w0 = hi ? m4l : m0;
      const u32 w1 = hi ? m4h : m1;
      const int lim = q - s0 - 4*hi;
      #pragma unroll
      for (int m = 0; m < 4; ++m) {
        u32 nib0 = (w0 >> (m*8)) & 15u;
        u32 nib1 = (w1 >> (m*8)) & 15u;
        if (diag) {
          int t0c = lim - m*8;       int c0 = min(max(t0c + 1, 0), 4);
          int t1c = lim - 32 - m*8;  int c1 = min(max(t1c + 1, 0), 4);
          nib0 |= (0xFu << c0) & 0xFu;
          nib1 |= (0xFu << c1) & 0xFu;
        }
        #pragma unroll
        for (int r = 0; r < 4; ++r) {
          if ((nib0 >> r) & 1) st0[m*4 + r] = NEGINF;
          if ((nib1 >> r) & 1) st1[m*4 + r] = NEGINF;
        }
      }
      // pairwise-tree max over 32 regs
      float t8[8];
      #pragma unroll
      for (int i = 0; i < 8; ++i)
        t8[i] = fmaxf(fmaxf(st0[i], st0[i+8]), fmaxf(st1[i], st1[i+8]));
      float t4a = fmaxf(t8[0], t8[4]), t4b = fmaxf(t8[1], t8[5]);
      float t4c = fmaxf(t8[2], t8[6]), t4d = fmaxf(t8[3], t8[7]);
      float rm = fmaxf(fmaxf(t4a, t4b), fmaxf(t4c, t4d));
      rm = fmaxf(rm, __shfl_xor(rm, 32, 64));
      const float mn = fmaxf(mrow, rm);
      const bool dead = (mn == NEGINF);
      const float sc = dead ? 1.f : EXP2F(mrow - mn);
      mrow = mn;
      float ps = 0.f;
      #pragma unroll
      for (int i = 0; i < 16; ++i) {
        float pv = dead ? 0.f : EXP2F(st0[i] - mn);
        st0[i] = pv; ps += pv;
      }
      #pragma unroll
      for (int i = 0; i < 16; ++i) {
        float pv = dead ? 0.f : EXP2F(st1[i] - mn);
        st1[i] = pv; ps += pv;
      }
      ps += __shfl_xor(ps, 32, 64);
      lrow = lrow * sc + ps;
      #pragma unroll
      for (int i = 0; i < 16; ++i) { cacc0[i] *= sc; cacc1[i] *= sc; }
    }

    // pack P to bf16 pairs (truncating): pk[m2][w] covers kv = m2*8 + 4*hi + 2w + {0,1}
    u32 pk[8][2];
    #pragma unroll
    for (int m = 0; m < 4; ++m) {
      pk[m][0]   = permpack(st0[m*4+0], st0[m*4+1]);
      pk[m][1]   = permpack(st0[m*4+2], st0[m*4+3]);
      pk[4+m][0] = permpack(st1[m*4+0], st1[m*4+1]);
      pk[4+m][1] = permpack(st1[m*4+2], st1[m*4+3]);
    }
    // B-operand frags: pf[ks][j] = P[q][kv = ks*16 + hi*8 + j]
    bf16x8 pf[4];
    #pragma unroll
    for (int ks = 0; ks < 4; ++ks) {
      u32 own0 = pk[2*ks][0],   own1 = pk[2*ks][1];
      u32 oth0 = pk[2*ks+1][0], oth1 = pk[2*ks+1][1];
      u32 r0 = __shfl_xor(hi ? own0 : oth0, 32, 64);
      u32 r1 = __shfl_xor(hi ? own1 : oth1, 32, 64);
      u32 w0 = hi ? r0 : own0;
      u32 w1 = hi ? r1 : own1;
      u32 w2 = hi ? oth0 : r0;
      u32 w3 = hi ? oth1 : r1;
      u32x4 wv = {w0, w1, w2, w3};
      pf[ks] = __builtin_bit_cast(bf16x8, wv);
    }

    // PV: ctx^T += V^T P^T
    __builtin_amdgcn_s_setprio(1);
    #pragma unroll
    for (int ks = 0; ks < 4; ++ks)
      cacc0 = __builtin_amdgcn_mfma_f32_32x32x16_bf16(vf[0][ks], pf[ks], cacc0, 0, 0, 0);
    #pragma unroll
    for (int ks = 0; ks < 4; ++ks)
      cacc1 = __builtin_amdgcn_mfma_f32_32x32x16_bf16(vf[1][ks], pf[ks], cacc1, 0, 0, 0);
    __builtin_amdgcn_s_setprio(0);

    kpmv_cur = kpmv_nxt;
  }

  if (NS == 1) {
    // direct epilogue: lane holds ctx^T[d = subd*32 + 4hi + 8m + r][q = l31]
    const bool dead = (lrow == 0.f);
    const float rl = dead ? 0.f : 1.f / lrow;
    #pragma unroll
    for (int subd = 0; subd < 2; ++subd) {
      #pragma unroll
      for (int m = 0; m < 4; ++m) {
        const int d0 = subd*32 + hi*4 + m*8;
        float v0 = (subd ? cacc1[m*4+0] : cacc0[m*4+0]) * rl;
        float v1 = (subd ? cacc1[m*4+1] : cacc0[m*4+1]) * rl;
        float v2 = (subd ? cacc1[m*4+2] : cacc0[m*4+2]) * rl;
        float v3 = (subd ? cacc1[m*4+3] : cacc0[m*4+3]) * rl;
        if (dead) {
          const float* vs = vsum + bh*64 + d0;
          v0 = vs[0] * (1.0f/2048.0f);
          v1 = vs[1] * (1.0f/2048.0f);
          v2 = vs[2] * (1.0f/2048.0f);
          v3 = vs[3] * (1.0f/2048.0f);
        }
        ushort4 o;
        o.x = f2bf(v0); o.y = f2bf(v1); o.z = f2bf(v2); o.w = f2bf(v3);
        *(ushort4*)(ctx2 + (size_t)(q*2 + b)*1024 + h*64 + d0) = o;
      }
    }
  } else {
    // partial epilogue: slot = ((bh*32) + (qt-32))*2 + ch
    const int slot = ((bh << 5) + (qt - 32))*2 + ch;
    u16* pc = pctx + (size_t)slot*2048 + (size_t)l31*64;
    #pragma unroll
    for (int subd = 0; subd < 2; ++subd) {
      #pragma unroll
      for (int m = 0; m < 4; ++m) {
        const int d0 = subd*32 + hi*4 + m*8;
        const f32x16& cc = subd ? cacc1 : cacc0;
        ushort4 o;
        o.x = f2bf(cc[m*4+0]); o.y = f2bf(cc[m*4+1]);
        o.z = f2bf(cc[m*4+2]); o.w = f2bf(cc[m*4+3]);
        *(ushort4*)(pc + d0) = o;
      }
    }
    if (!hi) {
      float2 ml; ml.x = mrow; ml.y = lrow;
      *(float2*)(pml + (size_t)slot*64 + l31*2) = ml;
    }
  }
}

// ---------------- combine partials for split tiles ----------------
// grid (32 qtm, 32 bh), 64 threads. lane: q = lane>>1, d-half = (lane&1)*32.
__global__ __launch_bounds__(64) void combine_kernel(
    const u16* __restrict__ pctx, const float* __restrict__ pml,
    const float* __restrict__ vsum, u16* __restrict__ ctx2)
{
  const int qtm = blockIdx.x, bh = blockIdx.y;
  const int qt = 32 + qtm;
  const int b = bh >> 4, h = bh & 15;
  const int lane = threadIdx.x;
  const int qr = lane >> 1, d0 = (lane & 1) * 32;
  const int slot0 = ((bh << 5) + qtm)*2;
  const float* ml0 = pml + (size_t)slot0*64 + qr*2;
  const float* ml1 = pml + (size_t)(slot0+1)*64 + qr*2;
  const float m1 = ml0[0], l1 = ml0[1];
  const float m2 = ml1[0], l2 = ml1[1];
  const float ms = fmaxf(m1, m2);
  bool dead = (ms == NEGINF);
  const float w1 = dead ? 0.f : EXP2F(m1 - ms);
  const float w2 = dead ? 0.f : EXP2F(m2 - ms);
  const float lt = w1*l1 + w2*l2;
  dead = dead || (lt == 0.f);
  const float rl = dead ? 0.f : 1.f / lt;
  const u16* c1 = pctx + ((size_t)slot0*32 + qr)*64 + d0;
  const u16* c2 = pctx + ((size_t)(slot0+1)*32 + qr)*64 + d0;
  const int qrow = qt*32 + qr;
  u16* dst = ctx2 + (size_t)(qrow*2 + b)*1024 + h*64 + d0;
  #pragma unroll
  for (int g2 = 0; g2 < 4; ++g2) {
    bf16x8 a = *(const bf16x8*)(c1 + g2*8);
    bf16x8 bb = *(const bf16x8*)(c2 + g2*8);
    bf16x8 o;
    #pragma unroll
    for (int j = 0; j < 8; ++j) {
      float v = (w1*bf2f((u16)a[j]) + w2*bf2f((u16)bb[j])) * rl;
      if (dead) v = vsum[bh*64 + d0 + g2*8 + j] * (1.0f/2048.0f);
      o[j] = (short)f2bf(v);
    }
    *(bf16x8*)(dst + g2*8) = o;
  }
}

extern "C" void kernel_launch(void* const* d_in, const int* in_sizes, int n_in,
                              void* d_out, int out_size, void* d_ws, size_t ws_size,
                              hipStream_t stream) {
  const float* query = (const float*)d_in[0];
  const int*   kpm   = (const int*)d_in[1];
  const float* Wq = (const float*)d_in[3];
  const float* bq = (const float*)d_in[4];
  const float* Wk = (const float*)d_in[5];
  const float* bk = (const float*)d_in[6];
  const float* Wv = (const float*)d_in[7];
  const float* bv = (const float*)d_in[8];
  const float* Wo = (const float*)d_in[9];
  const float* bo = (const float*)d_in[10];

  char* ws = (char*)d_ws;
  u16*   qbf  = (u16*)(ws);                  // [0,8M): query bf16 (dead after gemm_qkv)
  u16*   Vt   = (u16*)(ws);                  // [0,8M): V^T (aliases qbf, written after)
  u16*   wbf  = (u16*)(ws + 8388608);        // [8M,16M): weights bf16
  u16*   qkvh = (u16*)(ws + 16777216);       // [16M,40M): Q,K,V head-major
  u16*   pctx = (u16*)(ws + 33554432);       // [32M,40M): partials (aliases dead V-orig)
  u16*   ctx2 = (u16*)(ws + 41943040);       // [40M,48M): attn output [T*B][E]
  float* vsum = (float*)(ws + 50331648);     // [48M, +8K)
  float* pml  = (float*)(ws + 50339840);     // [48M+8K, +512K): partial m/l

  cvt_kernel<<<dim3(4096), 256, 0, stream>>>(query, qbf, 4194304);
  cvt4_kernel<<<dim3(1024, 4), 256, 0, stream>>>(Wq, Wk, Wv, Wo, wbf);

  hipMemsetAsync(vsum, 0, 2048 * sizeof(float), stream);

  gemm_qkv<<<dim3(32, 16, 3), 256, 0, stream>>>(qbf, wbf, bq, bk, bv, qkvh);
  vtrans_kernel<<<dim3(1024), 256, 0, stream>>>(qkvh + 2*4194304, Vt, vsum);
  flash_attn<<<dim3(3072), 64, 0, stream>>>(qkvh, qkvh + 1*4194304,
                                            Vt, kpm, vsum, ctx2, pctx, pml);
  combine_kernel<<<dim3(32, 32), 64, 0, stream>>>(pctx, pml, vsum, ctx2);
  gemm_out<<<dim3(32, 16), 256, 0, stream>>>(ctx2, wbf + 3*1048576, bo, (float*)d_out);
}

// Round 6
// 153.070 us; speedup vs baseline: 1.4082x; 1.4082x over previous
//
#include <hip/hip_runtime.h>
#include <hip/hip_bf16.h>
#include <stdint.h>

typedef unsigned short u16;
typedef uint32_t u32;
typedef unsigned long long u64;
typedef __attribute__((ext_vector_type(8))) short bf16x8;
typedef __attribute__((ext_vector_type(4))) float f32x4;
typedef __attribute__((ext_vector_type(16))) float f32x16;
typedef __attribute__((ext_vector_type(4))) u32 u32x4;

#define T_SEQ 2048

__device__ __forceinline__ float bf2f(u16 u) {
  union { u32 i; float f; } v; v.i = ((u32)u) << 16; return v.f;
}
__device__ __forceinline__ u16 f2bf(float f) {
  union { float f; u32 i; } v; v.f = f;
  u32 u = v.i;
  return (u16)((u + 0x7fffu + ((u >> 16) & 1u)) >> 16);
}

#if __has_builtin(__builtin_amdgcn_exp2f)
#define EXP2F(x) __builtin_amdgcn_exp2f(x)
#else
#define EXP2F(x) exp2f(x)
#endif

// truncating bf16 pair pack: {hi[31:16], lo[31:16]}
__device__ __forceinline__ u32 permpack(float lo, float hi) {
#if __has_builtin(__builtin_amdgcn_perm)
  return __builtin_amdgcn_perm(__float_as_uint(hi), __float_as_uint(lo), 0x07060302u);
#else
  return (__float_as_uint(hi) & 0xFFFF0000u) | (__float_as_uint(lo) >> 16);
#endif
}

__device__ __forceinline__ void gload_lds16(const void* g, void* l) {
  __builtin_amdgcn_global_load_lds(
      (const __attribute__((address_space(1))) void*)g,
      (__attribute__((address_space(3))) void*)l, 16, 0, 0);
}

// ---------------- fp32 -> bf16 converts ----------------
__global__ __launch_bounds__(256) void cvt_kernel(const float* __restrict__ src,
                                                  u16* __restrict__ dst, int n) {
  int i = (blockIdx.x * 256 + threadIdx.x) * 4;
  if (i + 3 < n) {
    const float4 v = *(const float4*)(src + i);
    ushort4 o;
    o.x = f2bf(v.x); o.y = f2bf(v.y); o.z = f2bf(v.z); o.w = f2bf(v.w);
    *(ushort4*)(dst + i) = o;
  }
}

__global__ __launch_bounds__(256) void cvt4_kernel(
    const float* __restrict__ s0, const float* __restrict__ s1,
    const float* __restrict__ s2, const float* __restrict__ s3,
    u16* __restrict__ dst) {
  const int z = blockIdx.y;
  const float* src = (z == 0) ? s0 : (z == 1) ? s1 : (z == 2) ? s2 : s3;
  int i = (blockIdx.x * 256 + threadIdx.x) * 4;
  const float4 v = *(const float4*)(src + i);
  ushort4 o;
  o.x = f2bf(v.x); o.y = f2bf(v.y); o.z = f2bf(v.z); o.w = f2bf(v.w);
  *(ushort4*)(dst + (size_t)z * 1048576 + i) = o;
}

// ---------------- GEMM core: C[128x64] += A[128xK] * B[64xK]^T, K=1024 ----
__device__ __forceinline__ void gemm_core_128x64(
    f32x4 acc[2][4], const u16* __restrict__ A, const u16* __restrict__ Bw,
    int bm, int bn, u16* As, u16* Bs)
{
  const int tid = threadIdx.x;
  const int w = tid >> 6, lane = tid & 63, g = lane >> 4, c = lane & 15;
  for (int k0 = 0; k0 < 1024; k0 += 64) {
    __syncthreads();
    #pragma unroll
    for (int is = 0; is < 4; ++is) {
      int o = (is*4 + w)*1024 + lane*16;
      int row = o >> 7, c16 = (o >> 4) & 7;
      gload_lds16(A + (size_t)(bm*128 + row)*1024 + k0 + (c16 ^ (row & 7))*8,
                  (char*)As + (is*4 + w)*1024);
    }
    #pragma unroll
    for (int is = 0; is < 2; ++is) {
      int o = (is*4 + w)*1024 + lane*16;
      int row = o >> 7, c16 = (o >> 4) & 7;
      gload_lds16(Bw + (size_t)(bn*64 + row)*1024 + k0 + (c16 ^ (row & 7))*8,
                  (char*)Bs + (is*4 + w)*1024);
    }
    __syncthreads();
    bf16x8 af[2][2], bfr[4][2];
    #pragma unroll
    for (int mf = 0; mf < 2; ++mf)
      #pragma unroll
      for (int kc = 0; kc < 2; ++kc) {
        int row = w*32 + mf*16 + c;
        int colb = kc*64 + g*16;
        af[mf][kc] = *(const bf16x8*)((const char*)As + row*128 + (colb ^ ((row & 7) << 4)));
      }
    #pragma unroll
    for (int nf = 0; nf < 4; ++nf)
      #pragma unroll
      for (int kc = 0; kc < 2; ++kc) {
        int row = nf*16 + c;
        int colb = kc*64 + g*16;
        bfr[nf][kc] = *(const bf16x8*)((const char*)Bs + row*128 + (colb ^ ((row & 7) << 4)));
      }
    #pragma unroll
    for (int mf = 0; mf < 2; ++mf)
      #pragma unroll
      for (int nf = 0; nf < 4; ++nf)
        #pragma unroll
        for (int kc = 0; kc < 2; ++kc)
          acc[mf][nf] = __builtin_amdgcn_mfma_f32_16x16x32_bf16(
              af[mf][kc], bfr[nf][kc], acc[mf][nf], 0, 0, 0);
  }
}

// ---------------- QKV projection ----------------
// Q is scaled by DH^-0.5 * log2(e) so attention softmax runs in exp2 domain.
__global__ __launch_bounds__(256, 2) void gemm_qkv(
    const u16* __restrict__ Abf, const u16* __restrict__ Wbf,
    const float* __restrict__ bq, const float* __restrict__ bk,
    const float* __restrict__ bv, u16* __restrict__ qkvh)
{
  __shared__ __align__(16) u16 As[128*64];
  __shared__ __align__(16) u16 Bs[64*64];
  f32x4 acc[2][4];
  #pragma unroll
  for (int mf = 0; mf < 2; ++mf)
    #pragma unroll
    for (int nf = 0; nf < 4; ++nf) acc[mf][nf] = (f32x4){0.f,0.f,0.f,0.f};
  const int z = blockIdx.z;
  gemm_core_128x64(acc, Abf, Wbf + (size_t)z*1048576, blockIdx.x, blockIdx.y, As, Bs);
  const float* bias = (z == 0) ? bq : (z == 1) ? bk : bv;
  const float scl = (z == 0) ? 0.18033688011112043f : 1.0f;  // 0.125 * log2(e)
  u16* dst = qkvh + (size_t)z * 4194304;
  const int tid = threadIdx.x, w = tid >> 6, lane = tid & 63, g = lane >> 4, c = lane & 15;
  #pragma unroll
  for (int mf = 0; mf < 2; ++mf)
    #pragma unroll
    for (int nf = 0; nf < 4; ++nf) {
      int col = blockIdx.y*64 + nf*16 + c;
      float bcol = bias[col];
      int h = col >> 6, d = col & 63;
      #pragma unroll
      for (int r = 0; r < 4; ++r) {
        int row = blockIdx.x*128 + w*32 + mf*16 + g*4 + r;
        int t = row >> 1, bb = row & 1;
        float v = (acc[mf][nf][r] + bcol) * scl;
        dst[(size_t)(bb*16 + h)*131072 + (size_t)t*64 + d] = f2bf(v);
      }
    }
}

// ---------------- output projection ----------------
__global__ __launch_bounds__(256, 2) void gemm_out(
    const u16* __restrict__ ctx2, const u16* __restrict__ Wobf,
    const float* __restrict__ bo, float* __restrict__ out)
{
  __shared__ __align__(16) u16 As[128*64];
  __shared__ __align__(16) u16 Bs[64*64];
  f32x4 acc[2][4];
  #pragma unroll
  for (int mf = 0; mf < 2; ++mf)
    #pragma unroll
    for (int nf = 0; nf < 4; ++nf) acc[mf][nf] = (f32x4){0.f,0.f,0.f,0.f};
  gemm_core_128x64(acc, ctx2, Wobf, blockIdx.x, blockIdx.y, As, Bs);
  const int tid = threadIdx.x, w = tid >> 6, lane = tid & 63, g = lane >> 4, c = lane & 15;
  #pragma unroll
  for (int mf = 0; mf < 2; ++mf)
    #pragma unroll
    for (int nf = 0; nf < 4; ++nf) {
      int col = blockIdx.y*64 + nf*16 + c;
      float bcol = bo[col];
      #pragma unroll
      for (int r = 0; r < 4; ++r) {
        int row = blockIdx.x*128 + w*32 + mf*16 + g*4 + r;
        out[(size_t)row*1024 + col] = acc[mf][nf][r] + bcol;
      }
    }
}

// ---------------- V transpose + column sums ----------------
__global__ __launch_bounds__(256) void vtrans_kernel(const u16* __restrict__ Vh,
                                                     u16* __restrict__ Vt,
                                                     float* __restrict__ vs) {
  __shared__ u16 tile[64][72];
  const int bh = blockIdx.x >> 5, tc = blockIdx.x & 31;
  const int t0 = tc * 64;
  const int tid = threadIdx.x;
  {
    const int tl = tid >> 2, d0 = (tid & 3) * 16;
    const u16* src = Vh + (size_t)bh*131072 + (size_t)(t0 + tl)*64 + d0;
    bf16x8 a = *(const bf16x8*)src;
    bf16x8 b2 = *(const bf16x8*)(src + 8);
    #pragma unroll
    for (int j = 0; j < 8; ++j) {
      tile[d0 + j][tl] = (u16)a[j];
      tile[d0 + 8 + j][tl] = (u16)b2[j];
    }
  }
  __syncthreads();
  {
    const int d = tid >> 2, tq = (tid & 3) * 16;
    bf16x8 o0, o1;
    float s = 0.f;
    #pragma unroll
    for (int j = 0; j < 8; ++j) {
      u16 x0 = tile[d][tq + j], x1 = tile[d][tq + 8 + j];
      o0[j] = (short)x0; o1[j] = (short)x1;
      s += bf2f(x0) + bf2f(x1);
    }
    u16* dst = Vt + (size_t)bh*131072 + (size_t)d*2048 + t0 + tq;
    *(bf16x8*)dst = o0;
    *(bf16x8*)(dst + 8) = o1;
    s += __shfl_xor(s, 1, 64);
    s += __shfl_xor(s, 2, 64);
    if ((tid & 3) == 0) atomicAdd(&vs[bh*64 + d], s);
  }
}

// ---------------- flash attention: KV-split flash-decoding ----------------
// grid 3072 = 8 XCD x 4 bh x 96 (qt,chunk) pairs. 1-wave blocks, no LDS/barriers.
// qt<32: single chunk, writes ctx2 directly. qt>=32: 2 chunks, each writes
// unnormalized partial (bf16 cacc, f32 m/l); combine_kernel merges.
// Scores are in exp2 domain (log2e folded into Q scale).
// launch_bounds (64,2): live state ~90 VGPR; (64,4) capped at 64 and SPILLED
// (R5: WRITE_SIZE 276MB, FETCH 6x) -- do not raise the min-waves arg.
#define ZERO16 (f32x16){0.f,0.f,0.f,0.f,0.f,0.f,0.f,0.f,0.f,0.f,0.f,0.f,0.f,0.f,0.f,0.f}
#define NEGINF (-__builtin_inff())

__global__ __launch_bounds__(64, 2) void flash_attn(
    const u16* __restrict__ Qh, const u16* __restrict__ Kh,
    const u16* __restrict__ Vt, const int* __restrict__ kpm,
    const float* __restrict__ vsum, u16* __restrict__ ctx2,
    u16* __restrict__ pctx, float* __restrict__ pml)
{
  const int lane = threadIdx.x;
  const int l31 = lane & 31, hi = lane >> 5;

  const int id = blockIdx.x;
  const int xcd = id & 7, rest = id >> 3;
  const int bh = xcd * 4 + (rest & 3);
  const int pp = rest >> 2;              // 0..95
  int qt, ch, NS;
  if (pp < 32) { qt = pp; ch = 0; NS = 1; }
  else { int uu = pp - 32; qt = 32 + (uu >> 1); ch = uu & 1; NS = 2; }
  const int b = bh >> 4, h = bh & 15;
  const int q0 = qt * 32;
  const size_t hbase = (size_t)bh * 131072;
  const int nt = (qt >> 1) + 1;
  int lo, hicap;
  if (NS == 1) { lo = 0; hicap = nt; }
  else { int h1 = nt >> 1; lo = ch ? h1 : 0; hicap = ch ? nt : h1; }
  const int q = q0 + l31;

  // Q fragments (B-operand): lane holds Q[q][k = kt*16 + hi*8 + j]
  bf16x8 qfrag[4];
  #pragma unroll
  for (int kt = 0; kt < 4; ++kt)
    qfrag[kt] = *(const bf16x8*)(Qh + hbase + (size_t)q*64 + kt*16 + hi*8);

  // K fragments (A-operand) for first tile
  bf16x8 kreg[2][4];
  #pragma unroll
  for (int sub = 0; sub < 2; ++sub)
    #pragma unroll
    for (int kt = 0; kt < 4; ++kt)
      kreg[sub][kt] = *(const bf16x8*)(Kh + hbase + (size_t)(lo*64 + sub*32 + l31)*64 + kt*16 + hi*8);

  int kpmv_cur = kpm[b*T_SEQ + lo*64 + lane];
  int kpmv_nxt = 0;

  float mrow = NEGINF, lrow = 0.f;
  f32x16 cacc0 = ZERO16, cacc1 = ZERO16;

  for (int t = lo; t < hicap; ++t) {
    const int s0 = t * 64;
    const bool notLast = (t + 1 < hicap);
    const bool diag = (t == nt - 1);

    // V^T fragments (A-operand): Vt[db*32 + l31][s0 + ks*16 + hi*8 + j]
    bf16x8 vf[2][4];
    #pragma unroll
    for (int db = 0; db < 2; ++db)
      #pragma unroll
      for (int ks = 0; ks < 4; ++ks)
        vf[db][ks] = *(const bf16x8*)(Vt + hbase + (size_t)(db*32 + l31)*2048 + s0 + ks*16 + hi*8);

    // S^T = K Q^T : lane owns q=l31; reg i: kv = s0 + sub*32 + 4*hi + (i&3) + 8*(i>>2)
    f32x16 st0 = ZERO16, st1 = ZERO16;
    __builtin_amdgcn_s_setprio(1);
    #pragma unroll
    for (int kt = 0; kt < 4; ++kt) {
      st0 = __builtin_amdgcn_mfma_f32_32x32x16_bf16(kreg[0][kt], qfrag[kt], st0, 0, 0, 0);
      st1 = __builtin_amdgcn_mfma_f32_32x32x16_bf16(kreg[1][kt], qfrag[kt], st1, 0, 0, 0);
    }
    __builtin_amdgcn_s_setprio(0);

    // prefetch K(t+1) + kpm(t+1)
    if (notLast) {
      #pragma unroll
      for (int sub = 0; sub < 2; ++sub)
        #pragma unroll
        for (int kt = 0; kt < 4; ++kt)
          kreg[sub][kt] = *(const bf16x8*)(Kh + hbase + (size_t)(s0 + 64 + sub*32 + l31)*64 + kt*16 + hi*8);
      kpmv_nxt = kpm[b*T_SEQ + s0 + 64 + lane];
    }

    // mask + online softmax (per-lane, exp2 domain)
    {
      const u64 mask = __ballot(kpmv_cur != 0);
      const u32 m0 = (u32)mask, m1 = (u32)(mask >> 32);
      const u64 m4 = mask >> 4;
      const u32 m4l = (u32)m4, m4h = (u32)(m4 >> 32);
      const u32 w0 = hi ? m4l : m0;
      const u32 w1 = hi ? m4h : m1;
      const int lim = q - s0 - 4*hi;
      #pragma unroll
      for (int m = 0; m < 4; ++m) {
        u32 nib0 = (w0 >> (m*8)) & 15u;
        u32 nib1 = (w1 >> (m*8)) & 15u;
        if (diag) {
          int t0c = lim - m*8;       int c0 = min(max(t0c + 1, 0), 4);
          int t1c = lim - 32 - m*8;  int c1 = min(max(t1c + 1, 0), 4);
          nib0 |= (0xFu << c0) & 0xFu;
          nib1 |= (0xFu << c1) & 0xFu;
        }
        #pragma unroll
        for (int r = 0; r < 4; ++r) {
          if ((nib0 >> r) & 1) st0[m*4 + r] = NEGINF;
          if ((nib1 >> r) & 1) st1[m*4 + r] = NEGINF;
        }
      }
      // pairwise-tree max over 32 regs
      float t8[8];
      #pragma unroll
      for (int i = 0; i < 8; ++i)
        t8[i] = fmaxf(fmaxf(st0[i], st0[i+8]), fmaxf(st1[i], st1[i+8]));
      float t4a = fmaxf(t8[0], t8[4]), t4b = fmaxf(t8[1], t8[5]);
      float t4c = fmaxf(t8[2], t8[6]), t4d = fmaxf(t8[3], t8[7]);
      float rm = fmaxf(fmaxf(t4a, t4b), fmaxf(t4c, t4d));
      rm = fmaxf(rm, __shfl_xor(rm, 32, 64));
      const float mn = fmaxf(mrow, rm);
      const bool dead = (mn == NEGINF);
      const float sc = dead ? 1.f : EXP2F(mrow - mn);
      mrow = mn;
      float ps = 0.f;
      #pragma unroll
      for (int i = 0; i < 16; ++i) {
        float pv = dead ? 0.f : EXP2F(st0[i] - mn);
        st0[i] = pv; ps += pv;
      }
      #pragma unroll
      for (int i = 0; i < 16; ++i) {
        float pv = dead ? 0.f : EXP2F(st1[i] - mn);
        st1[i] = pv; ps += pv;
      }
      ps += __shfl_xor(ps, 32, 64);
      lrow = lrow * sc + ps;
      #pragma unroll
      for (int i = 0; i < 16; ++i) { cacc0[i] *= sc; cacc1[i] *= sc; }
    }

    // pack P to bf16 pairs (truncating): pk[m2][w] covers kv = m2*8 + 4*hi + 2w + {0,1}
    u32 pk[8][2];
    #pragma unroll
    for (int m = 0; m < 4; ++m) {
      pk[m][0]   = permpack(st0[m*4+0], st0[m*4+1]);
      pk[m][1]   = permpack(st0[m*4+2], st0[m*4+3]);
      pk[4+m][0] = permpack(st1[m*4+0], st1[m*4+1]);
      pk[4+m][1] = permpack(st1[m*4+2], st1[m*4+3]);
    }
    // B-operand frags: pf[ks][j] = P[q][kv = ks*16 + hi*8 + j]
    bf16x8 pf[4];
    #pragma unroll
    for (int ks = 0; ks < 4; ++ks) {
      u32 own0 = pk[2*ks][0],   own1 = pk[2*ks][1];
      u32 oth0 = pk[2*ks+1][0], oth1 = pk[2*ks+1][1];
      u32 r0 = __shfl_xor(hi ? own0 : oth0, 32, 64);
      u32 r1 = __shfl_xor(hi ? own1 : oth1, 32, 64);
      u32 w0 = hi ? r0 : own0;
      u32 w1 = hi ? r1 : own1;
      u32 w2 = hi ? oth0 : r0;
      u32 w3 = hi ? oth1 : r1;
      u32x4 wv = {w0, w1, w2, w3};
      pf[ks] = __builtin_bit_cast(bf16x8, wv);
    }

    // PV: ctx^T += V^T P^T
    __builtin_amdgcn_s_setprio(1);
    #pragma unroll
    for (int ks = 0; ks < 4; ++ks)
      cacc0 = __builtin_amdgcn_mfma_f32_32x32x16_bf16(vf[0][ks], pf[ks], cacc0, 0, 0, 0);
    #pragma unroll
    for (int ks = 0; ks < 4; ++ks)
      cacc1 = __builtin_amdgcn_mfma_f32_32x32x16_bf16(vf[1][ks], pf[ks], cacc1, 0, 0, 0);
    __builtin_amdgcn_s_setprio(0);

    kpmv_cur = kpmv_nxt;
  }

  if (NS == 1) {
    // direct epilogue: lane holds ctx^T[d = subd*32 + 4hi + 8m + r][q = l31]
    const bool dead = (lrow == 0.f);
    const float rl = dead ? 0.f : 1.f / lrow;
    #pragma unroll
    for (int subd = 0; subd < 2; ++subd) {
      #pragma unroll
      for (int m = 0; m < 4; ++m) {
        const int d0 = subd*32 + hi*4 + m*8;
        float v0 = (subd ? cacc1[m*4+0] : cacc0[m*4+0]) * rl;
        float v1 = (subd ? cacc1[m*4+1] : cacc0[m*4+1]) * rl;
        float v2 = (subd ? cacc1[m*4+2] : cacc0[m*4+2]) * rl;
        float v3 = (subd ? cacc1[m*4+3] : cacc0[m*4+3]) * rl;
        if (dead) {
          const float* vs = vsum + bh*64 + d0;
          v0 = vs[0] * (1.0f/2048.0f);
          v1 = vs[1] * (1.0f/2048.0f);
          v2 = vs[2] * (1.0f/2048.0f);
          v3 = vs[3] * (1.0f/2048.0f);
        }
        ushort4 o;
        o.x = f2bf(v0); o.y = f2bf(v1); o.z = f2bf(v2); o.w = f2bf(v3);
        *(ushort4*)(ctx2 + (size_t)(q*2 + b)*1024 + h*64 + d0) = o;
      }
    }
  } else {
    // partial epilogue: slot = ((bh*32) + (qt-32))*2 + ch
    const int slot = ((bh << 5) + (qt - 32))*2 + ch;
    u16* pc = pctx + (size_t)slot*2048 + (size_t)l31*64;
    #pragma unroll
    for (int subd = 0; subd < 2; ++subd) {
      #pragma unroll
      for (int m = 0; m < 4; ++m) {
        const int d0 = subd*32 + hi*4 + m*8;
        const f32x16& cc = subd ? cacc1 : cacc0;
        ushort4 o;
        o.x = f2bf(cc[m*4+0]); o.y = f2bf(cc[m*4+1]);
        o.z = f2bf(cc[m*4+2]); o.w = f2bf(cc[m*4+3]);
        *(ushort4*)(pc + d0) = o;
      }
    }
    if (!hi) {
      float2 ml; ml.x = mrow; ml.y = lrow;
      *(float2*)(pml + (size_t)slot*64 + l31*2) = ml;
    }
  }
}

// ---------------- combine partials for split tiles ----------------
__global__ __launch_bounds__(64) void combine_kernel(
    const u16* __restrict__ pctx, const float* __restrict__ pml,
    const float* __restrict__ vsum, u16* __restrict__ ctx2)
{
  const int qtm = blockIdx.x, bh = blockIdx.y;
  const int qt = 32 + qtm;
  const int b = bh >> 4, h = bh & 15;
  const int lane = threadIdx.x;
  const int qr = lane >> 1, d0 = (lane & 1) * 32;
  const int slot0 = ((bh << 5) + qtm)*2;
  const float* ml0 = pml + (size_t)slot0*64 + qr*2;
  const float* ml1 = pml + (size_t)(slot0+1)*64 + qr*2;
  const float m1 = ml0[0], l1 = ml0[1];
  const float m2 = ml1[0], l2 = ml1[1];
  const float ms = fmaxf(m1, m2);
  bool dead = (ms == NEGINF);
  const float w1 = dead ? 0.f : EXP2F(m1 - ms);
  const float w2 = dead ? 0.f : EXP2F(m2 - ms);
  const float lt = w1*l1 + w2*l2;
  dead = dead || (lt == 0.f);
  const float rl = dead ? 0.f : 1.f / lt;
  const u16* c1 = pctx + ((size_t)slot0*32 + qr)*64 + d0;
  const u16* c2 = pctx + ((size_t)(slot0+1)*32 + qr)*64 + d0;
  const int qrow = qt*32 + qr;
  u16* dst = ctx2 + (size_t)(qrow*2 + b)*1024 + h*64 + d0;
  #pragma unroll
  for (int g2 = 0; g2 < 4; ++g2) {
    bf16x8 a = *(const bf16x8*)(c1 + g2*8);
    bf16x8 bb = *(const bf16x8*)(c2 + g2*8);
    bf16x8 o;
    #pragma unroll
    for (int j = 0; j < 8; ++j) {
      float v = (w1*bf2f((u16)a[j]) + w2*bf2f((u16)bb[j])) * rl;
      if (dead) v = vsum[bh*64 + d0 + g2*8 + j] * (1.0f/2048.0f);
      o[j] = (short)f2bf(v);
    }
    *(bf16x8*)(dst + g2*8) = o;
  }
}

extern "C" void kernel_launch(void* const* d_in, const int* in_sizes, int n_in,
                              void* d_out, int out_size, void* d_ws, size_t ws_size,
                              hipStream_t stream) {
  const float* query = (const float*)d_in[0];
  const int*   kpm   = (const int*)d_in[1];
  const float* Wq = (const float*)d_in[3];
  const float* bq = (const float*)d_in[4];
  const float* Wk = (const float*)d_in[5];
  const float* bk = (const float*)d_in[6];
  const float* Wv = (const float*)d_in[7];
  const float* bv = (const float*)d_in[8];
  const float* Wo = (const float*)d_in[9];
  const float* bo = (const float*)d_in[10];

  char* ws = (char*)d_ws;
  u16*   qbf  = (u16*)(ws);                  // [0,8M): query bf16 (dead after gemm_qkv)
  u16*   Vt   = (u16*)(ws);                  // [0,8M): V^T (aliases qbf, written after)
  u16*   wbf  = (u16*)(ws + 8388608);        // [8M,16M): weights bf16
  u16*   qkvh = (u16*)(ws + 16777216);       // [16M,40M): Q,K,V head-major
  u16*   pctx = (u16*)(ws + 33554432);       // [32M,40M): partials (aliases dead V-orig)
  u16*   ctx2 = (u16*)(ws + 41943040);       // [40M,48M): attn output [T*B][E]
  float* vsum = (float*)(ws + 50331648);     // [48M, +8K)
  float* pml  = (float*)(ws + 50339840);     // [48M+8K, +512K): partial m/l

  cvt_kernel<<<dim3(4096), 256, 0, stream>>>(query, qbf, 4194304);
  cvt4_kernel<<<dim3(1024, 4), 256, 0, stream>>>(Wq, Wk, Wv, Wo, wbf);

  hipMemsetAsync(vsum, 0, 2048 * sizeof(float), stream);

  gemm_qkv<<<dim3(32, 16, 3), 256, 0, stream>>>(qbf, wbf, bq, bk, bv, qkvh);
  vtrans_kernel<<<dim3(1024), 256, 0, stream>>>(qkvh + 2*4194304, Vt, vsum);
  flash_attn<<<dim3(3072), 64, 0, stream>>>(qkvh, qkvh + 1*4194304,
                                            Vt, kpm, vsum, ctx2, pctx, pml);
  combine_kernel<<<dim3(32, 32), 64, 0, stream>>>(pctx, pml, vsum, ctx2);
  gemm_out<<<dim3(32, 16), 256, 0, stream>>>(ctx2, wbf + 3*1048576, bo, (float*)d_out);
}

// Round 7
// 152.230 us; speedup vs baseline: 1.4160x; 1.0055x over previous
//
#include <hip/hip_runtime.h>
#include <hip/hip_bf16.h>
#include <stdint.h>

typedef unsigned short u16;
typedef uint32_t u32;
typedef unsigned long long u64;
typedef __attribute__((ext_vector_type(8))) short bf16x8;
typedef __attribute__((ext_vector_type(4))) float f32x4;
typedef __attribute__((ext_vector_type(16))) float f32x16;
typedef __attribute__((ext_vector_type(4))) u32 u32x4;

#define T_SEQ 2048

__device__ __forceinline__ float bf2f(u16 u) {
  union { u32 i; float f; } v; v.i = ((u32)u) << 16; return v.f;
}
__device__ __forceinline__ u16 f2bf(float f) {
  union { float f; u32 i; } v; v.f = f;
  u32 u = v.i;
  return (u16)((u + 0x7fffu + ((u >> 16) & 1u)) >> 16);
}

#if __has_builtin(__builtin_amdgcn_exp2f)
#define EXP2F(x) __builtin_amdgcn_exp2f(x)
#else
#define EXP2F(x) exp2f(x)
#endif

// truncating bf16 pair pack: {hi[31:16], lo[31:16]}
__device__ __forceinline__ u32 permpack(float lo, float hi) {
#if __has_builtin(__builtin_amdgcn_perm)
  return __builtin_amdgcn_perm(__float_as_uint(hi), __float_as_uint(lo), 0x07060302u);
#else
  return (__float_as_uint(hi) & 0xFFFF0000u) | (__float_as_uint(lo) >> 16);
#endif
}

__device__ __forceinline__ void gload_lds16(const void* g, void* l) {
  __builtin_amdgcn_global_load_lds(
      (const __attribute__((address_space(1))) void*)g,
      (__attribute__((address_space(3))) void*)l, 16, 0, 0);
}

// ---------------- fp32 -> bf16 converts ----------------
__global__ __launch_bounds__(256) void cvt_kernel(const float* __restrict__ src,
                                                  u16* __restrict__ dst, int n) {
  int i = (blockIdx.x * 256 + threadIdx.x) * 4;
  if (i + 3 < n) {
    const float4 v = *(const float4*)(src + i);
    ushort4 o;
    o.x = f2bf(v.x); o.y = f2bf(v.y); o.z = f2bf(v.z); o.w = f2bf(v.w);
    *(ushort4*)(dst + i) = o;
  }
}

__global__ __launch_bounds__(256) void cvt4_kernel(
    const float* __restrict__ s0, const float* __restrict__ s1,
    const float* __restrict__ s2, const float* __restrict__ s3,
    u16* __restrict__ dst) {
  const int z = blockIdx.y;
  const float* src = (z == 0) ? s0 : (z == 1) ? s1 : (z == 2) ? s2 : s3;
  int i = (blockIdx.x * 256 + threadIdx.x) * 4;
  const float4 v = *(const float4*)(src + i);
  ushort4 o;
  o.x = f2bf(v.x); o.y = f2bf(v.y); o.z = f2bf(v.z); o.w = f2bf(v.w);
  *(ushort4*)(dst + (size_t)z * 1048576 + i) = o;
}

// ------- GEMM core: C[128x128] += A[128xK] * B[128xK]^T, K=1024, 8 waves ---
// Same per-wave structure as the proven 128x64 core (acc[2][4], same swizzle),
// but 2x N per block and 8 waves (512 thr): 2x MFMA per staged byte, 2x TLP.
__device__ __forceinline__ void gemm_core_128x128(
    f32x4 acc[2][4], const u16* __restrict__ A, const u16* __restrict__ Bw,
    int bm, int bn, u16* As, u16* Bs)
{
  const int tid = threadIdx.x;
  const int w = tid >> 6, lane = tid & 63, g = lane >> 4, c = lane & 15;
  const int wr = (w & 3) * 32, wc = (w >> 2) * 64;
  for (int k0 = 0; k0 < 1024; k0 += 64) {
    __syncthreads();
    #pragma unroll
    for (int is = 0; is < 2; ++is) {
      int o = (is*8 + w)*1024 + lane*16;
      int row = o >> 7, c16 = (o >> 4) & 7;
      gload_lds16(A + (size_t)(bm*128 + row)*1024 + k0 + (c16 ^ (row & 7))*8,
                  (char*)As + (is*8 + w)*1024);
    }
    #pragma unroll
    for (int is = 0; is < 2; ++is) {
      int o = (is*8 + w)*1024 + lane*16;
      int row = o >> 7, c16 = (o >> 4) & 7;
      gload_lds16(Bw + (size_t)(bn*128 + row)*1024 + k0 + (c16 ^ (row & 7))*8,
                  (char*)Bs + (is*8 + w)*1024);
    }
    __syncthreads();
    bf16x8 af[2][2], bfr[4][2];
    #pragma unroll
    for (int mf = 0; mf < 2; ++mf)
      #pragma unroll
      for (int kc = 0; kc < 2; ++kc) {
        int row = wr + mf*16 + c;
        int colb = kc*64 + g*16;
        af[mf][kc] = *(const bf16x8*)((const char*)As + row*128 + (colb ^ ((row & 7) << 4)));
      }
    #pragma unroll
    for (int nf = 0; nf < 4; ++nf)
      #pragma unroll
      for (int kc = 0; kc < 2; ++kc) {
        int row = wc + nf*16 + c;
        int colb = kc*64 + g*16;
        bfr[nf][kc] = *(const bf16x8*)((const char*)Bs + row*128 + (colb ^ ((row & 7) << 4)));
      }
    #pragma unroll
    for (int mf = 0; mf < 2; ++mf)
      #pragma unroll
      for (int nf = 0; nf < 4; ++nf)
        #pragma unroll
        for (int kc = 0; kc < 2; ++kc)
          acc[mf][nf] = __builtin_amdgcn_mfma_f32_16x16x32_bf16(
              af[mf][kc], bfr[nf][kc], acc[mf][nf], 0, 0, 0);
  }
}

// ---------------- QKV projection (128x128 tile, 512 thr) ----------------
// Q is scaled by DH^-0.5 * log2(e) so attention softmax runs in exp2 domain.
__global__ __launch_bounds__(512, 2) void gemm_qkv(
    const u16* __restrict__ Abf, const u16* __restrict__ Wbf,
    const float* __restrict__ bq, const float* __restrict__ bk,
    const float* __restrict__ bv, u16* __restrict__ qkvh)
{
  __shared__ __align__(16) u16 As[128*64];
  __shared__ __align__(16) u16 Bs[128*64];
  f32x4 acc[2][4];
  #pragma unroll
  for (int mf = 0; mf < 2; ++mf)
    #pragma unroll
    for (int nf = 0; nf < 4; ++nf) acc[mf][nf] = (f32x4){0.f,0.f,0.f,0.f};
  const int z = blockIdx.z;
  gemm_core_128x128(acc, Abf, Wbf + (size_t)z*1048576, blockIdx.x, blockIdx.y, As, Bs);
  const float* bias = (z == 0) ? bq : (z == 1) ? bk : bv;
  const float scl = (z == 0) ? 0.18033688011112043f : 1.0f;  // 0.125 * log2(e)
  u16* dst = qkvh + (size_t)z * 4194304;
  const int tid = threadIdx.x, w = tid >> 6, lane = tid & 63, g = lane >> 4, c = lane & 15;
  const int wr = (w & 3) * 32, wc = (w >> 2) * 64;
  #pragma unroll
  for (int mf = 0; mf < 2; ++mf)
    #pragma unroll
    for (int nf = 0; nf < 4; ++nf) {
      int col = blockIdx.y*128 + wc + nf*16 + c;
      float bcol = bias[col];
      int h = col >> 6, d = col & 63;
      #pragma unroll
      for (int r = 0; r < 4; ++r) {
        int row = blockIdx.x*128 + wr + mf*16 + g*4 + r;
        int t = row >> 1, bb = row & 1;
        float v = (acc[mf][nf][r] + bcol) * scl;
        dst[(size_t)(bb*16 + h)*131072 + (size_t)t*64 + d] = f2bf(v);
      }
    }
}

// ---------------- output projection (128x128 tile, 512 thr) ----------------
__global__ __launch_bounds__(512, 2) void gemm_out(
    const u16* __restrict__ ctx2, const u16* __restrict__ Wobf,
    const float* __restrict__ bo, float* __restrict__ out)
{
  __shared__ __align__(16) u16 As[128*64];
  __shared__ __align__(16) u16 Bs[128*64];
  f32x4 acc[2][4];
  #pragma unroll
  for (int mf = 0; mf < 2; ++mf)
    #pragma unroll
    for (int nf = 0; nf < 4; ++nf) acc[mf][nf] = (f32x4){0.f,0.f,0.f,0.f};
  gemm_core_128x128(acc, ctx2, Wobf, blockIdx.x, blockIdx.y, As, Bs);
  const int tid = threadIdx.x, w = tid >> 6, lane = tid & 63, g = lane >> 4, c = lane & 15;
  const int wr = (w & 3) * 32, wc = (w >> 2) * 64;
  #pragma unroll
  for (int mf = 0; mf < 2; ++mf)
    #pragma unroll
    for (int nf = 0; nf < 4; ++nf) {
      int col = blockIdx.y*128 + wc + nf*16 + c;
      float bcol = bo[col];
      #pragma unroll
      for (int r = 0; r < 4; ++r) {
        int row = blockIdx.x*128 + wr + mf*16 + g*4 + r;
        out[(size_t)row*1024 + col] = acc[mf][nf][r] + bcol;
      }
    }
}

// ---------------- V transpose + column sums ----------------
__global__ __launch_bounds__(256) void vtrans_kernel(const u16* __restrict__ Vh,
                                                     u16* __restrict__ Vt,
                                                     float* __restrict__ vs) {
  __shared__ u16 tile[64][72];
  const int bh = blockIdx.x >> 5, tc = blockIdx.x & 31;
  const int t0 = tc * 64;
  const int tid = threadIdx.x;
  {
    const int tl = tid >> 2, d0 = (tid & 3) * 16;
    const u16* src = Vh + (size_t)bh*131072 + (size_t)(t0 + tl)*64 + d0;
    bf16x8 a = *(const bf16x8*)src;
    bf16x8 b2 = *(const bf16x8*)(src + 8);
    #pragma unroll
    for (int j = 0; j < 8; ++j) {
      tile[d0 + j][tl] = (u16)a[j];
      tile[d0 + 8 + j][tl] = (u16)b2[j];
    }
  }
  __syncthreads();
  {
    const int d = tid >> 2, tq = (tid & 3) * 16;
    bf16x8 o0, o1;
    float s = 0.f;
    #pragma unroll
    for (int j = 0; j < 8; ++j) {
      u16 x0 = tile[d][tq + j], x1 = tile[d][tq + 8 + j];
      o0[j] = (short)x0; o1[j] = (short)x1;
      s += bf2f(x0) + bf2f(x1);
    }
    u16* dst = Vt + (size_t)bh*131072 + (size_t)d*2048 + t0 + tq;
    *(bf16x8*)dst = o0;
    *(bf16x8*)(dst + 8) = o1;
    s += __shfl_xor(s, 1, 64);
    s += __shfl_xor(s, 2, 64);
    if ((tid & 3) == 0) atomicAdd(&vs[bh*64 + d], s);
  }
}

// ---------------- flash attention: KV-split flash-decoding ----------------
// grid 3072 = 8 XCD x 4 bh x 96 (qt,chunk). 1-wave blocks, no LDS/barriers.
// Scores in exp2 domain. T13 defer-rescale (THR=8) + tree-sum ps shorten the
// per-iter serial chain. launch_bounds (64,2): (64,4) spilled in R5.
#define ZERO16 (f32x16){0.f,0.f,0.f,0.f,0.f,0.f,0.f,0.f,0.f,0.f,0.f,0.f,0.f,0.f,0.f,0.f}
#define NEGINF (-__builtin_inff())

__global__ __launch_bounds__(64, 2) void flash_attn(
    const u16* __restrict__ Qh, const u16* __restrict__ Kh,
    const u16* __restrict__ Vt, const int* __restrict__ kpm,
    const float* __restrict__ vsum, u16* __restrict__ ctx2,
    u16* __restrict__ pctx, float* __restrict__ pml)
{
  const int lane = threadIdx.x;
  const int l31 = lane & 31, hi = lane >> 5;

  const int id = blockIdx.x;
  const int xcd = id & 7, rest = id >> 3;
  const int bh = xcd * 4 + (rest & 3);
  const int pp = rest >> 2;              // 0..95
  int qt, ch, NS;
  if (pp < 32) { qt = pp; ch = 0; NS = 1; }
  else { int uu = pp - 32; qt = 32 + (uu >> 1); ch = uu & 1; NS = 2; }
  const int b = bh >> 4, h = bh & 15;
  const int q0 = qt * 32;
  const size_t hbase = (size_t)bh * 131072;
  const int nt = (qt >> 1) + 1;
  int lo, hicap;
  if (NS == 1) { lo = 0; hicap = nt; }
  else { int h1 = nt >> 1; lo = ch ? h1 : 0; hicap = ch ? nt : h1; }
  const int q = q0 + l31;

  // Q fragments (B-operand): lane holds Q[q][k = kt*16 + hi*8 + j]
  bf16x8 qfrag[4];
  #pragma unroll
  for (int kt = 0; kt < 4; ++kt)
    qfrag[kt] = *(const bf16x8*)(Qh + hbase + (size_t)q*64 + kt*16 + hi*8);

  // K fragments (A-operand) for first tile
  bf16x8 kreg[2][4];
  #pragma unroll
  for (int sub = 0; sub < 2; ++sub)
    #pragma unroll
    for (int kt = 0; kt < 4; ++kt)
      kreg[sub][kt] = *(const bf16x8*)(Kh + hbase + (size_t)(lo*64 + sub*32 + l31)*64 + kt*16 + hi*8);

  int kpmv_cur = kpm[b*T_SEQ + lo*64 + lane];
  int kpmv_nxt = 0;

  float mrow = NEGINF, lrow = 0.f;
  f32x16 cacc0 = ZERO16, cacc1 = ZERO16;

  for (int t = lo; t < hicap; ++t) {
    const int s0 = t * 64;
    const bool notLast = (t + 1 < hicap);
    const bool diag = (t == nt - 1);

    // V^T fragments (A-operand): Vt[db*32 + l31][s0 + ks*16 + hi*8 + j]
    bf16x8 vf[2][4];
    #pragma unroll
    for (int db = 0; db < 2; ++db)
      #pragma unroll
      for (int ks = 0; ks < 4; ++ks)
        vf[db][ks] = *(const bf16x8*)(Vt + hbase + (size_t)(db*32 + l31)*2048 + s0 + ks*16 + hi*8);

    // S^T = K Q^T : lane owns q=l31; reg i: kv = s0 + sub*32 + 4*hi + (i&3) + 8*(i>>2)
    f32x16 st0 = ZERO16, st1 = ZERO16;
    __builtin_amdgcn_s_setprio(1);
    #pragma unroll
    for (int kt = 0; kt < 4; ++kt) {
      st0 = __builtin_amdgcn_mfma_f32_32x32x16_bf16(kreg[0][kt], qfrag[kt], st0, 0, 0, 0);
      st1 = __builtin_amdgcn_mfma_f32_32x32x16_bf16(kreg[1][kt], qfrag[kt], st1, 0, 0, 0);
    }
    __builtin_amdgcn_s_setprio(0);

    // prefetch K(t+1) + kpm(t+1)
    if (notLast) {
      #pragma unroll
      for (int sub = 0; sub < 2; ++sub)
        #pragma unroll
        for (int kt = 0; kt < 4; ++kt)
          kreg[sub][kt] = *(const bf16x8*)(Kh + hbase + (size_t)(s0 + 64 + sub*32 + l31)*64 + kt*16 + hi*8);
      kpmv_nxt = kpm[b*T_SEQ + s0 + 64 + lane];
    }

    // mask + online softmax (per-lane, exp2 domain, defer-rescale)
    {
      const u64 mask = __ballot(kpmv_cur != 0);
      const u32 m0 = (u32)mask, m1 = (u32)(mask >> 32);
      const u64 m4 = mask >> 4;
      const u32 m4l = (u32)m4, m4h = (u32)(m4 >> 32);
      const u32 w0 = hi ? m4l : m0;
      const u32 w1 = hi ? m4h : m1;
      const int lim = q - s0 - 4*hi;
      #pragma unroll
      for (int m = 0; m < 4; ++m) {
        u32 nib0 = (w0 >> (m*8)) & 15u;
        u32 nib1 = (w1 >> (m*8)) & 15u;
        if (diag) {
          int t0c = lim - m*8;       int c0 = min(max(t0c + 1, 0), 4);
          int t1c = lim - 32 - m*8;  int c1 = min(max(t1c + 1, 0), 4);
          nib0 |= (0xFu << c0) & 0xFu;
          nib1 |= (0xFu << c1) & 0xFu;
        }
        #pragma unroll
        for (int r = 0; r < 4; ++r) {
          if ((nib0 >> r) & 1) st0[m*4 + r] = NEGINF;
          if ((nib1 >> r) & 1) st1[m*4 + r] = NEGINF;
        }
      }
      // pairwise-tree max over 32 regs
      float t8[8];
      #pragma unroll
      for (int i = 0; i < 8; ++i)
        t8[i] = fmaxf(fmaxf(st0[i], st0[i+8]), fmaxf(st1[i], st1[i+8]));
      float t4a = fmaxf(t8[0], t8[4]), t4b = fmaxf(t8[1], t8[5]);
      float t4c = fmaxf(t8[2], t8[6]), t4d = fmaxf(t8[3], t8[7]);
      float rm = fmaxf(fmaxf(t4a, t4b), fmaxf(t4c, t4d));
      rm = fmaxf(rm, __shfl_xor(rm, 32, 64));

      // T13 defer-rescale: only rescale when some lane's max grew by >8
      // (exp2 units; P then bounded by 2^8, f32 accum absorbs it)
      const bool need = (rm > mrow + 8.f) || (mrow < -1e30f);
      if (__any(need)) {
        const float mn = fmaxf(mrow, rm);
        const float sc = (mn < -1e30f) ? 1.f : EXP2F(mrow - mn);
        mrow = mn;
        lrow *= sc;
        #pragma unroll
        for (int i = 0; i < 16; ++i) { cacc0[i] *= sc; cacc1[i] *= sc; }
      }
      const bool dead = (mrow < -1e30f);
      // tree-sum ps: 4 parallel accumulators, not a 32-deep serial chain
      float a0 = 0.f, a1 = 0.f, a2 = 0.f, a3 = 0.f;
      #pragma unroll
      for (int i = 0; i < 16; i += 4) {
        float p0 = dead ? 0.f : EXP2F(st0[i+0] - mrow); st0[i+0] = p0; a0 += p0;
        float p1 = dead ? 0.f : EXP2F(st0[i+1] - mrow); st0[i+1] = p1; a1 += p1;
        float p2 = dead ? 0.f : EXP2F(st0[i+2] - mrow); st0[i+2] = p2; a2 += p2;
        float p3 = dead ? 0.f : EXP2F(st0[i+3] - mrow); st0[i+3] = p3; a3 += p3;
      }
      #pragma unroll
      for (int i = 0; i < 16; i += 4) {
        float p0 = dead ? 0.f : EXP2F(st1[i+0] - mrow); st1[i+0] = p0; a0 += p0;
        float p1 = dead ? 0.f : EXP2F(st1[i+1] - mrow); st1[i+1] = p1; a1 += p1;
        float p2 = dead ? 0.f : EXP2F(st1[i+2] - mrow); st1[i+2] = p2; a2 += p2;
        float p3 = dead ? 0.f : EXP2F(st1[i+3] - mrow); st1[i+3] = p3; a3 += p3;
      }
      float ps = (a0 + a1) + (a2 + a3);
      ps += __shfl_xor(ps, 32, 64);
      lrow += ps;
    }

    // pack P to bf16 pairs (truncating): pk[m2][w] covers kv = m2*8 + 4*hi + 2w + {0,1}
    u32 pk[8][2];
    #pragma unroll
    for (int m = 0; m < 4; ++m) {
      pk[m][0]   = permpack(st0[m*4+0], st0[m*4+1]);
      pk[m][1]   = permpack(st0[m*4+2], st0[m*4+3]);
      pk[4+m][0] = permpack(st1[m*4+0], st1[m*4+1]);
      pk[4+m][1] = permpack(st1[m*4+2], st1[m*4+3]);
    }
    // B-operand frags: pf[ks][j] = P[q][kv = ks*16 + hi*8 + j]
    bf16x8 pf[4];
    #pragma unroll
    for (int ks = 0; ks < 4; ++ks) {
      u32 own0 = pk[2*ks][0],   own1 = pk[2*ks][1];
      u32 oth0 = pk[2*ks+1][0], oth1 = pk[2*ks+1][1];
      u32 r0 = __shfl_xor(hi ? own0 : oth0, 32, 64);
      u32 r1 = __shfl_xor(hi ? own1 : oth1, 32, 64);
      u32 w0 = hi ? r0 : own0;
      u32 w1 = hi ? r1 : own1;
      u32 w2 = hi ? oth0 : r0;
      u32 w3 = hi ? oth1 : r1;
      u32x4 wv = {w0, w1, w2, w3};
      pf[ks] = __builtin_bit_cast(bf16x8, wv);
    }

    // PV: ctx^T += V^T P^T
    __builtin_amdgcn_s_setprio(1);
    #pragma unroll
    for (int ks = 0; ks < 4; ++ks)
      cacc0 = __builtin_amdgcn_mfma_f32_32x32x16_bf16(vf[0][ks], pf[ks], cacc0, 0, 0, 0);
    #pragma unroll
    for (int ks = 0; ks < 4; ++ks)
      cacc1 = __builtin_amdgcn_mfma_f32_32x32x16_bf16(vf[1][ks], pf[ks], cacc1, 0, 0, 0);
    __builtin_amdgcn_s_setprio(0);

    kpmv_cur = kpmv_nxt;
  }

  if (NS == 1) {
    // direct epilogue: lane holds ctx^T[d = subd*32 + 4hi + 8m + r][q = l31]
    const bool dead = (lrow == 0.f);
    const float rl = dead ? 0.f : 1.f / lrow;
    #pragma unroll
    for (int subd = 0; subd < 2; ++subd) {
      #pragma unroll
      for (int m = 0; m < 4; ++m) {
        const int d0 = subd*32 + hi*4 + m*8;
        float v0 = (subd ? cacc1[m*4+0] : cacc0[m*4+0]) * rl;
        float v1 = (subd ? cacc1[m*4+1] : cacc0[m*4+1]) * rl;
        float v2 = (subd ? cacc1[m*4+2] : cacc0[m*4+2]) * rl;
        float v3 = (subd ? cacc1[m*4+3] : cacc0[m*4+3]) * rl;
        if (dead) {
          const float* vs = vsum + bh*64 + d0;
          v0 = vs[0] * (1.0f/2048.0f);
          v1 = vs[1] * (1.0f/2048.0f);
          v2 = vs[2] * (1.0f/2048.0f);
          v3 = vs[3] * (1.0f/2048.0f);
        }
        ushort4 o;
        o.x = f2bf(v0); o.y = f2bf(v1); o.z = f2bf(v2); o.w = f2bf(v3);
        *(ushort4*)(ctx2 + (size_t)(q*2 + b)*1024 + h*64 + d0) = o;
      }
    }
  } else {
    // partial epilogue: slot = ((bh*32) + (qt-32))*2 + ch
    const int slot = ((bh << 5) + (qt - 32))*2 + ch;
    u16* pc = pctx + (size_t)slot*2048 + (size_t)l31*64;
    #pragma unroll
    for (int subd = 0; subd < 2; ++subd) {
      #pragma unroll
      for (int m = 0; m < 4; ++m) {
        const int d0 = subd*32 + hi*4 + m*8;
        const f32x16& cc = subd ? cacc1 : cacc0;
        ushort4 o;
        o.x = f2bf(cc[m*4+0]); o.y = f2bf(cc[m*4+1]);
        o.z = f2bf(cc[m*4+2]); o.w = f2bf(cc[m*4+3]);
        *(ushort4*)(pc + d0) = o;
      }
    }
    if (!hi) {
      float2 ml; ml.x = mrow; ml.y = lrow;
      *(float2*)(pml + (size_t)slot*64 + l31*2) = ml;
    }
  }
}

// ---------------- combine partials for split tiles ----------------
__global__ __launch_bounds__(64) void combine_kernel(
    const u16* __restrict__ pctx, const float* __restrict__ pml,
    const float* __restrict__ vsum, u16* __restrict__ ctx2)
{
  const int qtm = blockIdx.x, bh = blockIdx.y;
  const int qt = 32 + qtm;
  const int b = bh >> 4, h = bh & 15;
  const int lane = threadIdx.x;
  const int qr = lane >> 1, d0 = (lane & 1) * 32;
  const int slot0 = ((bh << 5) + qtm)*2;
  const float* ml0 = pml + (size_t)slot0*64 + qr*2;
  const float* ml1 = pml + (size_t)(slot0+1)*64 + qr*2;
  const float m1 = ml0[0], l1 = ml0[1];
  const float m2 = ml1[0], l2 = ml1[1];
  const float ms = fmaxf(m1, m2);
  bool dead = (ms == NEGINF);
  const float w1 = dead ? 0.f : EXP2F(m1 - ms);
  const float w2 = dead ? 0.f : EXP2F(m2 - ms);
  const float lt = w1*l1 + w2*l2;
  dead = dead || (lt == 0.f);
  const float rl = dead ? 0.f : 1.f / lt;
  const u16* c1 = pctx + ((size_t)slot0*32 + qr)*64 + d0;
  const u16* c2 = pctx + ((size_t)(slot0+1)*32 + qr)*64 + d0;
  const int qrow = qt*32 + qr;
  u16* dst = ctx2 + (size_t)(qrow*2 + b)*1024 + h*64 + d0;
  #pragma unroll
  for (int g2 = 0; g2 < 4; ++g2) {
    bf16x8 a = *(const bf16x8*)(c1 + g2*8);
    bf16x8 bb = *(const bf16x8*)(c2 + g2*8);
    bf16x8 o;
    #pragma unroll
    for (int j = 0; j < 8; ++j) {
      float v = (w1*bf2f((u16)a[j]) + w2*bf2f((u16)bb[j])) * rl;
      if (dead) v = vsum[bh*64 + d0 + g2*8 + j] * (1.0f/2048.0f);
      o[j] = (short)f2bf(v);
    }
    *(bf16x8*)(dst + g2*8) = o;
  }
}

extern "C" void kernel_launch(void* const* d_in, const int* in_sizes, int n_in,
                              void* d_out, int out_size, void* d_ws, size_t ws_size,
                              hipStream_t stream) {
  const float* query = (const float*)d_in[0];
  const int*   kpm   = (const int*)d_in[1];
  const float* Wq = (const float*)d_in[3];
  const float* bq = (const float*)d_in[4];
  const float* Wk = (const float*)d_in[5];
  const float* bk = (const float*)d_in[6];
  const float* Wv = (const float*)d_in[7];
  const float* bv = (const float*)d_in[8];
  const float* Wo = (const float*)d_in[9];
  const float* bo = (const float*)d_in[10];

  char* ws = (char*)d_ws;
  u16*   qbf  = (u16*)(ws);                  // [0,8M): query bf16 (dead after gemm_qkv)
  u16*   Vt   = (u16*)(ws);                  // [0,8M): V^T (aliases qbf, written after)
  u16*   wbf  = (u16*)(ws + 8388608);        // [8M,16M): weights bf16
  u16*   qkvh = (u16*)(ws + 16777216);       // [16M,40M): Q,K,V head-major
  u16*   pctx = (u16*)(ws + 33554432);       // [32M,40M): partials (aliases dead V-orig)
  u16*   ctx2 = (u16*)(ws + 41943040);       // [40M,48M): attn output [T*B][E]
  float* vsum = (float*)(ws + 50331648);     // [48M, +8K)
  float* pml  = (float*)(ws + 50339840);     // [48M+8K, +512K): partial m/l

  cvt_kernel<<<dim3(4096), 256, 0, stream>>>(query, qbf, 4194304);
  cvt4_kernel<<<dim3(1024, 4), 256, 0, stream>>>(Wq, Wk, Wv, Wo, wbf);

  hipMemsetAsync(vsum, 0, 2048 * sizeof(float), stream);

  gemm_qkv<<<dim3(32, 8, 3), 512, 0, stream>>>(qbf, wbf, bq, bk, bv, qkvh);
  vtrans_kernel<<<dim3(1024), 256, 0, stream>>>(qkvh + 2*4194304, Vt, vsum);
  flash_attn<<<dim3(3072), 64, 0, stream>>>(qkvh, qkvh + 1*4194304,
                                            Vt, kpm, vsum, ctx2, pctx, pml);
  combine_kernel<<<dim3(32, 32), 64, 0, stream>>>(pctx, pml, vsum, ctx2);
  gemm_out<<<dim3(32, 8), 512, 0, stream>>>(ctx2, wbf + 3*1048576, bo, (float*)d_out);
}

// Round 8
// 133.715 us; speedup vs baseline: 1.6120x; 1.1385x over previous
//
#include <hip/hip_runtime.h>
#include <hip/hip_bf16.h>
#include <stdint.h>

typedef unsigned short u16;
typedef uint32_t u32;
typedef unsigned long long u64;
typedef __attribute__((ext_vector_type(8))) short bf16x8;
typedef __attribute__((ext_vector_type(4))) float f32x4;
typedef __attribute__((ext_vector_type(16))) float f32x16;
typedef __attribute__((ext_vector_type(4))) u32 u32x4;

#define T_SEQ 2048

__device__ __forceinline__ float bf2f(u16 u) {
  union { u32 i; float f; } v; v.i = ((u32)u) << 16; return v.f;
}
__device__ __forceinline__ u16 f2bf(float f) {
  union { float f; u32 i; } v; v.f = f;
  u32 u = v.i;
  return (u16)((u + 0x7fffu + ((u >> 16) & 1u)) >> 16);
}

#if __has_builtin(__builtin_amdgcn_exp2f)
#define EXP2F(x) __builtin_amdgcn_exp2f(x)
#else
#define EXP2F(x) exp2f(x)
#endif

// truncating bf16 pair pack: {hi[31:16], lo[31:16]}
__device__ __forceinline__ u32 permpack(float lo, float hi) {
#if __has_builtin(__builtin_amdgcn_perm)
  return __builtin_amdgcn_perm(__float_as_uint(hi), __float_as_uint(lo), 0x07060302u);
#else
  return (__float_as_uint(hi) & 0xFFFF0000u) | (__float_as_uint(lo) >> 16);
#endif
}

__device__ __forceinline__ void gload_lds16(const void* g, void* l) {
  __builtin_amdgcn_global_load_lds(
      (const __attribute__((address_space(1))) void*)g,
      (__attribute__((address_space(3))) void*)l, 16, 0, 0);
}

// ---------------- fp32 -> bf16 converts ----------------
__global__ __launch_bounds__(256) void cvt_kernel(const float* __restrict__ src,
                                                  u16* __restrict__ dst, int n) {
  int i = (blockIdx.x * 256 + threadIdx.x) * 4;
  if (i + 3 < n) {
    const float4 v = *(const float4*)(src + i);
    ushort4 o;
    o.x = f2bf(v.x); o.y = f2bf(v.y); o.z = f2bf(v.z); o.w = f2bf(v.w);
    *(ushort4*)(dst + i) = o;
  }
}

__global__ __launch_bounds__(256) void cvt4_kernel(
    const float* __restrict__ s0, const float* __restrict__ s1,
    const float* __restrict__ s2, const float* __restrict__ s3,
    u16* __restrict__ dst) {
  const int z = blockIdx.y;
  const float* src = (z == 0) ? s0 : (z == 1) ? s1 : (z == 2) ? s2 : s3;
  int i = (blockIdx.x * 256 + threadIdx.x) * 4;
  const float4 v = *(const float4*)(src + i);
  ushort4 o;
  o.x = f2bf(v.x); o.y = f2bf(v.y); o.z = f2bf(v.z); o.w = f2bf(v.w);
  *(ushort4*)(dst + (size_t)z * 1048576 + i) = o;
}

// ------- GEMM core: C[128x128] += A[128xK] * B[128xK]^T, K=1024, 8 waves ---
__device__ __forceinline__ void gemm_core_128x128(
    f32x4 acc[2][4], const u16* __restrict__ A, const u16* __restrict__ Bw,
    int bm, int bn, u16* As, u16* Bs)
{
  const int tid = threadIdx.x;
  const int w = tid >> 6, lane = tid & 63, g = lane >> 4, c = lane & 15;
  const int wr = (w & 3) * 32, wc = (w >> 2) * 64;
  for (int k0 = 0; k0 < 1024; k0 += 64) {
    __syncthreads();
    #pragma unroll
    for (int is = 0; is < 2; ++is) {
      int o = (is*8 + w)*1024 + lane*16;
      int row = o >> 7, c16 = (o >> 4) & 7;
      gload_lds16(A + (size_t)(bm*128 + row)*1024 + k0 + (c16 ^ (row & 7))*8,
                  (char*)As + (is*8 + w)*1024);
    }
    #pragma unroll
    for (int is = 0; is < 2; ++is) {
      int o = (is*8 + w)*1024 + lane*16;
      int row = o >> 7, c16 = (o >> 4) & 7;
      gload_lds16(Bw + (size_t)(bn*128 + row)*1024 + k0 + (c16 ^ (row & 7))*8,
                  (char*)Bs + (is*8 + w)*1024);
    }
    __syncthreads();
    bf16x8 af[2][2], bfr[4][2];
    #pragma unroll
    for (int mf = 0; mf < 2; ++mf)
      #pragma unroll
      for (int kc = 0; kc < 2; ++kc) {
        int row = wr + mf*16 + c;
        int colb = kc*64 + g*16;
        af[mf][kc] = *(const bf16x8*)((const char*)As + row*128 + (colb ^ ((row & 7) << 4)));
      }
    #pragma unroll
    for (int nf = 0; nf < 4; ++nf)
      #pragma unroll
      for (int kc = 0; kc < 2; ++kc) {
        int row = wc + nf*16 + c;
        int colb = kc*64 + g*16;
        bfr[nf][kc] = *(const bf16x8*)((const char*)Bs + row*128 + (colb ^ ((row & 7) << 4)));
      }
    #pragma unroll
    for (int mf = 0; mf < 2; ++mf)
      #pragma unroll
      for (int nf = 0; nf < 4; ++nf)
        #pragma unroll
        for (int kc = 0; kc < 2; ++kc)
          acc[mf][nf] = __builtin_amdgcn_mfma_f32_16x16x32_bf16(
              af[mf][kc], bfr[nf][kc], acc[mf][nf], 0, 0, 0);
  }
}

// ---------------- QKV projection: ONE dispatch over concat [3072][1024] ----
// Q cols (z==0) scaled by DH^-0.5 * log2(e) for exp2-domain softmax.
__global__ __launch_bounds__(512, 2) void gemm_qkv(
    const u16* __restrict__ Abf, const u16* __restrict__ Wbf,
    const float* __restrict__ bq, const float* __restrict__ bk,
    const float* __restrict__ bv, u16* __restrict__ qkvh)
{
  __shared__ __align__(16) u16 As[128*64];
  __shared__ __align__(16) u16 Bs[128*64];
  f32x4 acc[2][4];
  #pragma unroll
  for (int mf = 0; mf < 2; ++mf)
    #pragma unroll
    for (int nf = 0; nf < 4; ++nf) acc[mf][nf] = (f32x4){0.f,0.f,0.f,0.f};
  gemm_core_128x128(acc, Abf, Wbf, blockIdx.x, blockIdx.y, As, Bs);
  const int tid = threadIdx.x, w = tid >> 6, lane = tid & 63, g = lane >> 4, c = lane & 15;
  const int wr = (w & 3) * 32, wc = (w >> 2) * 64;
  #pragma unroll
  for (int mf = 0; mf < 2; ++mf)
    #pragma unroll
    for (int nf = 0; nf < 4; ++nf) {
      int col = blockIdx.y*128 + wc + nf*16 + c;      // 0..3071
      int z = col >> 10, colz = col & 1023;
      const float* bias = (z == 0) ? bq : (z == 1) ? bk : bv;
      float bcol = bias[colz];
      float scl = (z == 0) ? 0.18033688011112043f : 1.0f;  // 0.125 * log2(e)
      int h = colz >> 6, d = colz & 63;
      u16* dst = qkvh + (size_t)z * 4194304;
      #pragma unroll
      for (int r = 0; r < 4; ++r) {
        int row = blockIdx.x*128 + wr + mf*16 + g*4 + r;
        int t = row >> 1, bb = row & 1;
        float v = (acc[mf][nf][r] + bcol) * scl;
        dst[(size_t)(bb*16 + h)*131072 + (size_t)t*64 + d] = f2bf(v);
      }
    }
}

// ---------------- output projection (128x128 tile, 512 thr) ----------------
__global__ __launch_bounds__(512, 2) void gemm_out(
    const u16* __restrict__ ctx2, const u16* __restrict__ Wobf,
    const float* __restrict__ bo, float* __restrict__ out)
{
  __shared__ __align__(16) u16 As[128*64];
  __shared__ __align__(16) u16 Bs[128*64];
  f32x4 acc[2][4];
  #pragma unroll
  for (int mf = 0; mf < 2; ++mf)
    #pragma unroll
    for (int nf = 0; nf < 4; ++nf) acc[mf][nf] = (f32x4){0.f,0.f,0.f,0.f};
  gemm_core_128x128(acc, ctx2, Wobf, blockIdx.x, blockIdx.y, As, Bs);
  const int tid = threadIdx.x, w = tid >> 6, lane = tid & 63, g = lane >> 4, c = lane & 15;
  const int wr = (w & 3) * 32, wc = (w >> 2) * 64;
  #pragma unroll
  for (int mf = 0; mf < 2; ++mf)
    #pragma unroll
    for (int nf = 0; nf < 4; ++nf) {
      int col = blockIdx.y*128 + wc + nf*16 + c;
      float bcol = bo[col];
      #pragma unroll
      for (int r = 0; r < 4; ++r) {
        int row = blockIdx.x*128 + wr + mf*16 + g*4 + r;
        out[(size_t)row*1024 + col] = acc[mf][nf][r] + bcol;
      }
    }
}

// ---------------- V transpose + column sums ----------------
__global__ __launch_bounds__(256) void vtrans_kernel(const u16* __restrict__ Vh,
                                                     u16* __restrict__ Vt,
                                                     float* __restrict__ vs) {
  __shared__ u16 tile[64][72];
  const int bh = blockIdx.x >> 5, tc = blockIdx.x & 31;
  const int t0 = tc * 64;
  const int tid = threadIdx.x;
  {
    const int tl = tid >> 2, d0 = (tid & 3) * 16;
    const u16* src = Vh + (size_t)bh*131072 + (size_t)(t0 + tl)*64 + d0;
    bf16x8 a = *(const bf16x8*)src;
    bf16x8 b2 = *(const bf16x8*)(src + 8);
    #pragma unroll
    for (int j = 0; j < 8; ++j) {
      tile[d0 + j][tl] = (u16)a[j];
      tile[d0 + 8 + j][tl] = (u16)b2[j];
    }
  }
  __syncthreads();
  {
    const int d = tid >> 2, tq = (tid & 3) * 16;
    bf16x8 o0, o1;
    float s = 0.f;
    #pragma unroll
    for (int j = 0; j < 8; ++j) {
      u16 x0 = tile[d][tq + j], x1 = tile[d][tq + 8 + j];
      o0[j] = (short)x0; o1[j] = (short)x1;
      s += bf2f(x0) + bf2f(x1);
    }
    u16* dst = Vt + (size_t)bh*131072 + (size_t)d*2048 + t0 + tq;
    *(bf16x8*)dst = o0;
    *(bf16x8*)(dst + 8) = o1;
    s += __shfl_xor(s, 1, 64);
    s += __shfl_xor(s, 2, 64);
    if ((tid & 3) == 0) atomicAdd(&vs[bh*64 + d], s);
  }
}

// ---------------- flash attention: 2-wave blocks, LDS-staged K/V ----------
// grid 1536 = 8 XCD x 4 bh x 48 (k,ch); LPT order (heavy chunks first).
// Waves take paired q-tiles qt=2k (w=0) and 2k+1 (w=1): identical nt=k+1 ->
// lockstep barriers never idle a wave. K and V^T staged to LDS with the
// GEMM-proven pre-swizzled-source XOR pattern via coalesced global_load_lds
// (wave0: K, wave1: V^T), double-buffered, 2-phase pipeline.
// k>=16 splits KV range in 2 chunks -> partials + combine (slots unchanged).
#define ZERO16 (f32x16){0.f,0.f,0.f,0.f,0.f,0.f,0.f,0.f,0.f,0.f,0.f,0.f,0.f,0.f,0.f,0.f}
#define NEGINF (-__builtin_inff())

__global__ __launch_bounds__(128, 2) void flash_attn(
    const u16* __restrict__ Qh, const u16* __restrict__ Kh,
    const u16* __restrict__ Vt, const int* __restrict__ kpm,
    const float* __restrict__ vsum, u16* __restrict__ ctx2,
    u16* __restrict__ pctx, float* __restrict__ pml)
{
  __shared__ __align__(16) u16 Kl[2][4096];
  __shared__ __align__(16) u16 Vl[2][4096];

  const int tid = threadIdx.x;
  const int w = tid >> 6, lane = tid & 63;
  const int l31 = lane & 31, hi = lane >> 5;

  const int id = blockIdx.x;
  const int xcd = id & 7, rest = id >> 3;
  const int bh = xcd * 4 + (rest & 3);
  const int pr = rest >> 2;              // 0..47, LPT-ordered
  int k, ch, NS;
  if (pr < 32) { k = 31 - (pr >> 1); ch = pr & 1; NS = 2; }
  else         { k = 47 - pr;        ch = 0;      NS = 1; }
  const int nt = k + 1;
  const int b = bh >> 4, h = bh & 15;
  const size_t hbase = (size_t)bh * 131072;
  int lo, hicap;
  if (NS == 1) { lo = 0; hicap = nt; }
  else { int h1 = nt >> 1; lo = ch ? h1 : 0; hicap = ch ? nt : h1; }
  const int q = k*64 + w*32 + l31;

  // Q fragments (B-operand): lane holds Q[q][kt*16 + hi*8 + j]
  bf16x8 qfrag[4];
  #pragma unroll
  for (int kt = 0; kt < 4; ++kt)
    qfrag[kt] = *(const bf16x8*)(Qh + hbase + (size_t)q*64 + kt*16 + hi*8);

  // prologue: stage tile lo into buffer 0 (wave0: K, wave1: V^T)
  {
    const int s0t = lo * 64;
    if (w == 0) {
      #pragma unroll
      for (int is = 0; is < 8; ++is) {
        int o = is*1024 + lane*16;
        int row = o >> 7, c16 = (o >> 4) & 7;
        gload_lds16(Kh + hbase + (size_t)(s0t + row)*64 + (c16 ^ (row & 7))*8,
                    (char*)Kl[0] + is*1024);
      }
    } else {
      #pragma unroll
      for (int is = 0; is < 8; ++is) {
        int o = is*1024 + lane*16;
        int row = o >> 7, c16 = (o >> 4) & 7;
        gload_lds16(Vt + hbase + (size_t)row*2048 + s0t + (c16 ^ (row & 7))*8,
                    (char*)Vl[0] + is*1024);
      }
    }
  }
  int kpmv_cur = kpm[b*T_SEQ + lo*64 + lane];
  int kpmv_nxt = 0;
  __syncthreads();

  float mrow = NEGINF, lrow = 0.f;
  f32x16 cacc0 = ZERO16, cacc1 = ZERO16;

  for (int t = lo; t < hicap; ++t) {
    const int cur = (t - lo) & 1, nxt = cur ^ 1;
    const int s0 = t * 64;
    const bool notLast = (t + 1 < hicap);
    const bool diag = (t == nt - 1);

    // stage tile t+1 into nxt
    if (notLast) {
      const int s0n = s0 + 64;
      if (w == 0) {
        #pragma unroll
        for (int is = 0; is < 8; ++is) {
          int o = is*1024 + lane*16;
          int row = o >> 7, c16 = (o >> 4) & 7;
          gload_lds16(Kh + hbase + (size_t)(s0n + row)*64 + (c16 ^ (row & 7))*8,
                      (char*)Kl[nxt] + is*1024);
        }
      } else {
        #pragma unroll
        for (int is = 0; is < 8; ++is) {
          int o = is*1024 + lane*16;
          int row = o >> 7, c16 = (o >> 4) & 7;
          gload_lds16(Vt + hbase + (size_t)row*2048 + s0n + (c16 ^ (row & 7))*8,
                      (char*)Vl[nxt] + is*1024);
        }
      }
      kpmv_nxt = kpm[b*T_SEQ + s0n + lane];
    }

    // fragments from LDS (swizzled read matches staged layout)
    bf16x8 kreg[2][4], vf[2][4];
    #pragma unroll
    for (int sub = 0; sub < 2; ++sub)
      #pragma unroll
      for (int kt = 0; kt < 4; ++kt) {
        int row = sub*32 + l31;
        int colb = kt*32 + hi*16;
        kreg[sub][kt] = *(const bf16x8*)((const char*)Kl[cur] + row*128 + (colb ^ ((row & 7) << 4)));
        vf[sub][kt]   = *(const bf16x8*)((const char*)Vl[cur] + row*128 + (colb ^ ((row & 7) << 4)));
      }

    // S^T = K Q^T : lane owns q; reg i: kv = s0 + sub*32 + 4*hi + (i&3) + 8*(i>>2)
    f32x16 st0 = ZERO16, st1 = ZERO16;
    __builtin_amdgcn_s_setprio(1);
    #pragma unroll
    for (int kt = 0; kt < 4; ++kt) {
      st0 = __builtin_amdgcn_mfma_f32_32x32x16_bf16(kreg[0][kt], qfrag[kt], st0, 0, 0, 0);
      st1 = __builtin_amdgcn_mfma_f32_32x32x16_bf16(kreg[1][kt], qfrag[kt], st1, 0, 0, 0);
    }
    __builtin_amdgcn_s_setprio(0);

    // mask + online softmax (per-lane, exp2 domain, defer-rescale)
    {
      const u64 mask = __ballot(kpmv_cur != 0);
      const u32 m0 = (u32)mask, m1 = (u32)(mask >> 32);
      const u64 m4 = mask >> 4;
      const u32 m4l = (u32)m4, m4h = (u32)(m4 >> 32);
      const u32 w0 = hi ? m4l : m0;
      const u32 w1 = hi ? m4h : m1;
      const int lim = q - s0 - 4*hi;
      #pragma unroll
      for (int m = 0; m < 4; ++m) {
        u32 nib0 = (w0 >> (m*8)) & 15u;
        u32 nib1 = (w1 >> (m*8)) & 15u;
        if (diag) {
          int t0c = lim - m*8;       int c0 = min(max(t0c + 1, 0), 4);
          int t1c = lim - 32 - m*8;  int c1 = min(max(t1c + 1, 0), 4);
          nib0 |= (0xFu << c0) & 0xFu;
          nib1 |= (0xFu << c1) & 0xFu;
        }
        #pragma unroll
        for (int r = 0; r < 4; ++r) {
          if ((nib0 >> r) & 1) st0[m*4 + r] = NEGINF;
          if ((nib1 >> r) & 1) st1[m*4 + r] = NEGINF;
        }
      }
      float t8[8];
      #pragma unroll
      for (int i = 0; i < 8; ++i)
        t8[i] = fmaxf(fmaxf(st0[i], st0[i+8]), fmaxf(st1[i], st1[i+8]));
      float t4a = fmaxf(t8[0], t8[4]), t4b = fmaxf(t8[1], t8[5]);
      float t4c = fmaxf(t8[2], t8[6]), t4d = fmaxf(t8[3], t8[7]);
      float rm = fmaxf(fmaxf(t4a, t4b), fmaxf(t4c, t4d));
      rm = fmaxf(rm, __shfl_xor(rm, 32, 64));

      const bool need = (rm > mrow + 8.f) || (mrow < -1e30f);
      if (__any(need)) {
        const float mn = fmaxf(mrow, rm);
        const float sc = (mn < -1e30f) ? 1.f : EXP2F(mrow - mn);
        mrow = mn;
        lrow *= sc;
        #pragma unroll
        for (int i = 0; i < 16; ++i) { cacc0[i] *= sc; cacc1[i] *= sc; }
      }
      const bool dead = (mrow < -1e30f);
      float a0 = 0.f, a1 = 0.f, a2 = 0.f, a3 = 0.f;
      #pragma unroll
      for (int i = 0; i < 16; i += 4) {
        float p0 = dead ? 0.f : EXP2F(st0[i+0] - mrow); st0[i+0] = p0; a0 += p0;
        float p1 = dead ? 0.f : EXP2F(st0[i+1] - mrow); st0[i+1] = p1; a1 += p1;
        float p2 = dead ? 0.f : EXP2F(st0[i+2] - mrow); st0[i+2] = p2; a2 += p2;
        float p3 = dead ? 0.f : EXP2F(st0[i+3] - mrow); st0[i+3] = p3; a3 += p3;
      }
      #pragma unroll
      for (int i = 0; i < 16; i += 4) {
        float p0 = dead ? 0.f : EXP2F(st1[i+0] - mrow); st1[i+0] = p0; a0 += p0;
        float p1 = dead ? 0.f : EXP2F(st1[i+1] - mrow); st1[i+1] = p1; a1 += p1;
        float p2 = dead ? 0.f : EXP2F(st1[i+2] - mrow); st1[i+2] = p2; a2 += p2;
        float p3 = dead ? 0.f : EXP2F(st1[i+3] - mrow); st1[i+3] = p3; a3 += p3;
      }
      float ps = (a0 + a1) + (a2 + a3);
      ps += __shfl_xor(ps, 32, 64);
      lrow += ps;
    }

    // pack P to bf16 pairs (truncating)
    u32 pk[8][2];
    #pragma unroll
    for (int m = 0; m < 4; ++m) {
      pk[m][0]   = permpack(st0[m*4+0], st0[m*4+1]);
      pk[m][1]   = permpack(st0[m*4+2], st0[m*4+3]);
      pk[4+m][0] = permpack(st1[m*4+0], st1[m*4+1]);
      pk[4+m][1] = permpack(st1[m*4+2], st1[m*4+3]);
    }
    // B-operand frags: pf[ks][j] = P[q][kv = ks*16 + hi*8 + j]
    bf16x8 pf[4];
    #pragma unroll
    for (int ks = 0; ks < 4; ++ks) {
      u32 own0 = pk[2*ks][0],   own1 = pk[2*ks][1];
      u32 oth0 = pk[2*ks+1][0], oth1 = pk[2*ks+1][1];
      u32 r0 = __shfl_xor(hi ? own0 : oth0, 32, 64);
      u32 r1 = __shfl_xor(hi ? own1 : oth1, 32, 64);
      u32 w0 = hi ? r0 : own0;
      u32 w1 = hi ? r1 : own1;
      u32 w2 = hi ? oth0 : r0;
      u32 w3 = hi ? oth1 : r1;
      u32x4 wv = {w0, w1, w2, w3};
      pf[ks] = __builtin_bit_cast(bf16x8, wv);
    }

    // PV: ctx^T += V^T P^T
    __builtin_amdgcn_s_setprio(1);
    #pragma unroll
    for (int ks = 0; ks < 4; ++ks)
      cacc0 = __builtin_amdgcn_mfma_f32_32x32x16_bf16(vf[0][ks], pf[ks], cacc0, 0, 0, 0);
    #pragma unroll
    for (int ks = 0; ks < 4; ++ks)
      cacc1 = __builtin_amdgcn_mfma_f32_32x32x16_bf16(vf[1][ks], pf[ks], cacc1, 0, 0, 0);
    __builtin_amdgcn_s_setprio(0);

    kpmv_cur = kpmv_nxt;
    if (notLast) __syncthreads();
  }

  const int qt32 = 2*k + w;
  if (NS == 1) {
    // direct epilogue: lane holds ctx^T[d = subd*32 + 4hi + 8m + r][q]
    const bool dead = (lrow == 0.f);
    const float rl = dead ? 0.f : 1.f / lrow;
    #pragma unroll
    for (int subd = 0; subd < 2; ++subd) {
      #pragma unroll
      for (int m = 0; m < 4; ++m) {
        const int d0 = subd*32 + hi*4 + m*8;
        float v0 = (subd ? cacc1[m*4+0] : cacc0[m*4+0]) * rl;
        float v1 = (subd ? cacc1[m*4+1] : cacc0[m*4+1]) * rl;
        float v2 = (subd ? cacc1[m*4+2] : cacc0[m*4+2]) * rl;
        float v3 = (subd ? cacc1[m*4+3] : cacc0[m*4+3]) * rl;
        if (dead) {
          const float* vs = vsum + bh*64 + d0;
          v0 = vs[0] * (1.0f/2048.0f);
          v1 = vs[1] * (1.0f/2048.0f);
          v2 = vs[2] * (1.0f/2048.0f);
          v3 = vs[3] * (1.0f/2048.0f);
        }
        ushort4 o;
        o.x = f2bf(v0); o.y = f2bf(v1); o.z = f2bf(v2); o.w = f2bf(v3);
        *(ushort4*)(ctx2 + (size_t)(q*2 + b)*1024 + h*64 + d0) = o;
      }
    }
  } else {
    // partial epilogue: slot = ((bh*32) + (qt32-32))*2 + ch
    const int slot = ((bh << 5) + (qt32 - 32))*2 + ch;
    u16* pc = pctx + (size_t)slot*2048 + (size_t)l31*64;
    #pragma unroll
    for (int subd = 0; subd < 2; ++subd) {
      #pragma unroll
      for (int m = 0; m < 4; ++m) {
        const int d0 = subd*32 + hi*4 + m*8;
        const f32x16& cc = subd ? cacc1 : cacc0;
        ushort4 o;
        o.x = f2bf(cc[m*4+0]); o.y = f2bf(cc[m*4+1]);
        o.z = f2bf(cc[m*4+2]); o.w = f2bf(cc[m*4+3]);
        *(ushort4*)(pc + d0) = o;
      }
    }
    if (!hi) {
      float2 ml; ml.x = mrow; ml.y = lrow;
      *(float2*)(pml + (size_t)slot*64 + l31*2) = ml;
    }
  }
}

// ---------------- combine partials for split tiles ----------------
__global__ __launch_bounds__(64) void combine_kernel(
    const u16* __restrict__ pctx, const float* __restrict__ pml,
    const float* __restrict__ vsum, u16* __restrict__ ctx2)
{
  const int qtm = blockIdx.x, bh = blockIdx.y;
  const int qt = 32 + qtm;
  const int b = bh >> 4, h = bh & 15;
  const int lane = threadIdx.x;
  const int qr = lane >> 1, d0 = (lane & 1) * 32;
  const int slot0 = ((bh << 5) + qtm)*2;
  const float* ml0 = pml + (size_t)slot0*64 + qr*2;
  const float* ml1 = pml + (size_t)(slot0+1)*64 + qr*2;
  const float m1 = ml0[0], l1 = ml0[1];
  const float m2 = ml1[0], l2 = ml1[1];
  const float ms = fmaxf(m1, m2);
  bool dead = (ms == NEGINF);
  const float w1 = dead ? 0.f : EXP2F(m1 - ms);
  const float w2 = dead ? 0.f : EXP2F(m2 - ms);
  const float lt = w1*l1 + w2*l2;
  dead = dead || (lt == 0.f);
  const float rl = dead ? 0.f : 1.f / lt;
  const u16* c1 = pctx + ((size_t)slot0*32 + qr)*64 + d0;
  const u16* c2 = pctx + ((size_t)(slot0+1)*32 + qr)*64 + d0;
  const int qrow = qt*32 + qr;
  u16* dst = ctx2 + (size_t)(qrow*2 + b)*1024 + h*64 + d0;
  #pragma unroll
  for (int g2 = 0; g2 < 4; ++g2) {
    bf16x8 a = *(const bf16x8*)(c1 + g2*8);
    bf16x8 bb = *(const bf16x8*)(c2 + g2*8);
    bf16x8 o;
    #pragma unroll
    for (int j = 0; j < 8; ++j) {
      float v = (w1*bf2f((u16)a[j]) + w2*bf2f((u16)bb[j])) * rl;
      if (dead) v = vsum[bh*64 + d0 + g2*8 + j] * (1.0f/2048.0f);
      o[j] = (short)f2bf(v);
    }
    *(bf16x8*)(dst + g2*8) = o;
  }
}

extern "C" void kernel_launch(void* const* d_in, const int* in_sizes, int n_in,
                              void* d_out, int out_size, void* d_ws, size_t ws_size,
                              hipStream_t stream) {
  const float* query = (const float*)d_in[0];
  const int*   kpm   = (const int*)d_in[1];
  const float* Wq = (const float*)d_in[3];
  const float* bq = (const float*)d_in[4];
  const float* Wk = (const float*)d_in[5];
  const float* bk = (const float*)d_in[6];
  const float* Wv = (const float*)d_in[7];
  const float* bv = (const float*)d_in[8];
  const float* Wo = (const float*)d_in[9];
  const float* bo = (const float*)d_in[10];

  char* ws = (char*)d_ws;
  u16*   qbf  = (u16*)(ws);                  // [0,8M): query bf16 (dead after gemm_qkv)
  u16*   Vt   = (u16*)(ws);                  // [0,8M): V^T (aliases qbf, written after)
  u16*   wbf  = (u16*)(ws + 8388608);        // [8M,16M): weights bf16 (Wq,Wk,Wv,Wo)
  u16*   qkvh = (u16*)(ws + 16777216);       // [16M,40M): Q,K,V head-major
  u16*   pctx = (u16*)(ws + 33554432);       // [32M,40M): partials (aliases dead V-orig)
  u16*   ctx2 = (u16*)(ws + 41943040);       // [40M,48M): attn output [T*B][E]
  float* vsum = (float*)(ws + 50331648);     // [48M, +8K)
  float* pml  = (float*)(ws + 50339840);     // [48M+8K, +512K): partial m/l

  cvt_kernel<<<dim3(4096), 256, 0, stream>>>(query, qbf, 4194304);
  cvt4_kernel<<<dim3(1024, 4), 256, 0, stream>>>(Wq, Wk, Wv, Wo, wbf);

  hipMemsetAsync(vsum, 0, 2048 * sizeof(float), stream);

  gemm_qkv<<<dim3(32, 24), 512, 0, stream>>>(qbf, wbf, bq, bk, bv, qkvh);
  vtrans_kernel<<<dim3(1024), 256, 0, stream>>>(qkvh + 2*4194304, Vt, vsum);
  flash_attn<<<dim3(1536), 128, 0, stream>>>(qkvh, qkvh + 1*4194304,
                                             Vt, kpm, vsum, ctx2, pctx, pml);
  combine_kernel<<<dim3(32, 32), 64, 0, stream>>>(pctx, pml, vsum, ctx2);
  gemm_out<<<dim3(32, 8), 512, 0, stream>>>(ctx2, wbf + 3*1048576, bo, (float*)d_out);
}